// Round 1
// baseline (2773.048 us; speedup 1.0000x reference)
//
#include <hip/hip_runtime.h>
#include <math.h>

#define N_NODES 50000
#define E_EDGES 800000
#define ET (E_EDGES + N_NODES)   // edges + self loops
#define IN_F 256
#define HID 128
#define HEADS1 8
#define C1 16
#define OUT_F 64
#define NEG_SLOPE 0.2f

__device__ __forceinline__ float lrelu(float v) { return v > 0.f ? v : NEG_SLOPE * v; }

// ---------------- GEMM1: h1[N,128] = x[N,256] @ W1[256,128] ----------------
__global__ __launch_bounds__(256) void gemm1_kernel(const float* __restrict__ x,
                                                    const float* __restrict__ W,
                                                    float* __restrict__ h1) {
  __shared__ float As[64][32];
  __shared__ float Bs[32][132];   // padded row stride (132*4=528B, 16B-aligned, bank shift 4)
  const int t = threadIdx.x;
  const int row0 = blockIdx.x * 64;
  const int rg = t >> 5;          // 8 row-groups of 8 rows
  const int cg = t & 31;          // col group: cols 4cg..4cg+3
  float acc[8][4];
#pragma unroll
  for (int i = 0; i < 8; ++i)
#pragma unroll
    for (int j = 0; j < 4; ++j) acc[i][j] = 0.f;

  const int ar = t >> 2;          // A staging: row in tile (0..63)
  const int ak = (t & 3) * 8;     // k offset {0,8,16,24}
  const int arow = row0 + ar;
  const int bkk = t >> 3;         // B staging: k row (0..31)
  const int bn = (t & 7) * 16;    // col offset

  for (int k0 = 0; k0 < IN_F; k0 += 32) {
    float4 av0, av1;
    if (arow < N_NODES) {
      const float4* ap = (const float4*)&x[(size_t)arow * IN_F + k0 + ak];
      av0 = ap[0]; av1 = ap[1];
    } else {
      av0 = make_float4(0.f, 0.f, 0.f, 0.f); av1 = av0;
    }
    *(float4*)&As[ar][ak]     = av0;
    *(float4*)&As[ar][ak + 4] = av1;

    const float* wp = &W[(size_t)(k0 + bkk) * HID + bn];
    float4 bv0 = *(const float4*)(wp + 0);
    float4 bv1 = *(const float4*)(wp + 4);
    float4 bv2 = *(const float4*)(wp + 8);
    float4 bv3 = *(const float4*)(wp + 12);
    *(float4*)&Bs[bkk][bn + 0]  = bv0;
    *(float4*)&Bs[bkk][bn + 4]  = bv1;
    *(float4*)&Bs[bkk][bn + 8]  = bv2;
    *(float4*)&Bs[bkk][bn + 12] = bv3;
    __syncthreads();

#pragma unroll
    for (int kk = 0; kk < 32; kk += 4) {
      float b[4][4];
#pragma unroll
      for (int j = 0; j < 4; ++j) {
        float4 bb = *(const float4*)&Bs[kk + j][cg * 4];
        b[j][0] = bb.x; b[j][1] = bb.y; b[j][2] = bb.z; b[j][3] = bb.w;
      }
#pragma unroll
      for (int i = 0; i < 8; ++i) {
        float4 aa = *(const float4*)&As[8 * rg + i][kk];
#pragma unroll
        for (int j = 0; j < 4; ++j) {
          acc[i][j] += aa.x * b[0][j] + aa.y * b[1][j] + aa.z * b[2][j] + aa.w * b[3][j];
        }
      }
    }
    __syncthreads();
  }
#pragma unroll
  for (int i = 0; i < 8; ++i) {
    int row = row0 + 8 * rg + i;
    if (row < N_NODES) {
      float4 v = make_float4(acc[i][0], acc[i][1], acc[i][2], acc[i][3]);
      *(float4*)&h1[(size_t)row * HID + cg * 4] = v;
    }
  }
}

// ---------------- GEMM2: h2[N,64] = in[N,128] @ W2[128,64] ----------------
__global__ __launch_bounds__(256) void gemm2_kernel(const float* __restrict__ in,
                                                    const float* __restrict__ W,
                                                    float* __restrict__ h2) {
  __shared__ float As[64][32];
  __shared__ float Bs[32][68];    // padded (68*4=272B, 16B-aligned)
  const int t = threadIdx.x;
  const int row0 = blockIdx.x * 64;
  const int rg = t >> 4;          // 16 row-groups of 4 rows
  const int cg = t & 15;          // cols 4cg..4cg+3
  float acc[4][4];
#pragma unroll
  for (int i = 0; i < 4; ++i)
#pragma unroll
    for (int j = 0; j < 4; ++j) acc[i][j] = 0.f;

  const int ar = t >> 2;
  const int ak = (t & 3) * 8;
  const int arow = row0 + ar;
  const int bkk = t >> 3;         // 0..31
  const int bn = (t & 7) * 8;     // 0..56

  for (int k0 = 0; k0 < HID; k0 += 32) {
    float4 av0, av1;
    if (arow < N_NODES) {
      const float4* ap = (const float4*)&in[(size_t)arow * HID + k0 + ak];
      av0 = ap[0]; av1 = ap[1];
    } else {
      av0 = make_float4(0.f, 0.f, 0.f, 0.f); av1 = av0;
    }
    *(float4*)&As[ar][ak]     = av0;
    *(float4*)&As[ar][ak + 4] = av1;

    const float* wp = &W[(size_t)(k0 + bkk) * OUT_F + bn];
    float4 bv0 = *(const float4*)(wp + 0);
    float4 bv1 = *(const float4*)(wp + 4);
    *(float4*)&Bs[bkk][bn + 0] = bv0;
    *(float4*)&Bs[bkk][bn + 4] = bv1;
    __syncthreads();

#pragma unroll
    for (int kk = 0; kk < 32; kk += 4) {
      float b[4][4];
#pragma unroll
      for (int j = 0; j < 4; ++j) {
        float4 bb = *(const float4*)&Bs[kk + j][cg * 4];
        b[j][0] = bb.x; b[j][1] = bb.y; b[j][2] = bb.z; b[j][3] = bb.w;
      }
#pragma unroll
      for (int i = 0; i < 4; ++i) {
        float4 aa = *(const float4*)&As[4 * rg + i][kk];
#pragma unroll
        for (int j = 0; j < 4; ++j) {
          acc[i][j] += aa.x * b[0][j] + aa.y * b[1][j] + aa.z * b[2][j] + aa.w * b[3][j];
        }
      }
    }
    __syncthreads();
  }
#pragma unroll
  for (int i = 0; i < 4; ++i) {
    int row = row0 + 4 * rg + i;
    if (row < N_NODES) {
      float4 v = make_float4(acc[i][0], acc[i][1], acc[i][2], acc[i][3]);
      *(float4*)&h2[(size_t)row * OUT_F + cg * 4] = v;
    }
  }
}

// ---------------- att1: a_s[N,8], a_d[N,8] from h1[N,128] ----------------
__global__ __launch_bounds__(256) void att1_kernel(const float* __restrict__ h1,
                                                   const float* __restrict__ att_src,
                                                   const float* __restrict__ att_dst,
                                                   float* __restrict__ a_s,
                                                   float* __restrict__ a_d) {
  int wid = (blockIdx.x * 256 + threadIdx.x) >> 6;  // node per wave
  int lane = threadIdx.x & 63;
  if (wid >= N_NODES) return;
  float2 h  = *(const float2*)&h1[(size_t)wid * HID + 2 * lane];
  float2 as = *(const float2*)&att_src[2 * lane];
  float2 ad = *(const float2*)&att_dst[2 * lane];
  float vs = h.x * as.x + h.y * as.y;
  float vd = h.x * ad.x + h.y * ad.y;
  // reduce within 8-lane groups (one head per group: head = lane/8)
  vs += __shfl_xor(vs, 1); vd += __shfl_xor(vd, 1);
  vs += __shfl_xor(vs, 2); vd += __shfl_xor(vd, 2);
  vs += __shfl_xor(vs, 4); vd += __shfl_xor(vd, 4);
  if ((lane & 7) == 0) {
    a_s[wid * HEADS1 + (lane >> 3)] = vs;
    a_d[wid * HEADS1 + (lane >> 3)] = vd;
  }
}

// ---------------- att2: a_s[N], a_d[N] from h2[N,64] ----------------
__global__ __launch_bounds__(256) void att2_kernel(const float* __restrict__ h2,
                                                   const float* __restrict__ att_src,
                                                   const float* __restrict__ att_dst,
                                                   float* __restrict__ a_s,
                                                   float* __restrict__ a_d) {
  int wid = (blockIdx.x * 256 + threadIdx.x) >> 6;
  int lane = threadIdx.x & 63;
  if (wid >= N_NODES) return;
  float h = h2[(size_t)wid * OUT_F + lane];
  float vs = h * att_src[lane];
  float vd = h * att_dst[lane];
#pragma unroll
  for (int m = 1; m < 64; m <<= 1) { vs += __shfl_xor(vs, m); vd += __shfl_xor(vd, m); }
  if (lane == 0) { a_s[wid] = vs; a_d[wid] = vd; }
}

// ---------------- edge softmax denominators ----------------
__global__ __launch_bounds__(256) void edge_denom1_kernel(const int* __restrict__ ei,
                                                          const float* __restrict__ a_s,
                                                          const float* __restrict__ a_d,
                                                          float* __restrict__ denom) {
  int e = blockIdx.x * 256 + threadIdx.x;
  if (e >= ET) return;
  int s, d;
  if (e < E_EDGES) { s = ei[e]; d = ei[E_EDGES + e]; }
  else { s = d = e - E_EDGES; }
  const float* ps = &a_s[(size_t)s * HEADS1];
  const float* pd = &a_d[(size_t)d * HEADS1];
  float4 s0 = *(const float4*)(ps);
  float4 s1 = *(const float4*)(ps + 4);
  float4 d0 = *(const float4*)(pd);
  float4 d1 = *(const float4*)(pd + 4);
  float* dn = &denom[(size_t)d * HEADS1];
  atomicAdd(dn + 0, __expf(lrelu(s0.x + d0.x)));
  atomicAdd(dn + 1, __expf(lrelu(s0.y + d0.y)));
  atomicAdd(dn + 2, __expf(lrelu(s0.z + d0.z)));
  atomicAdd(dn + 3, __expf(lrelu(s0.w + d0.w)));
  atomicAdd(dn + 4, __expf(lrelu(s1.x + d1.x)));
  atomicAdd(dn + 5, __expf(lrelu(s1.y + d1.y)));
  atomicAdd(dn + 6, __expf(lrelu(s1.z + d1.z)));
  atomicAdd(dn + 7, __expf(lrelu(s1.w + d1.w)));
}

__global__ __launch_bounds__(256) void edge_denom2_kernel(const int* __restrict__ ei,
                                                          const float* __restrict__ a_s,
                                                          const float* __restrict__ a_d,
                                                          float* __restrict__ denom) {
  int e = blockIdx.x * 256 + threadIdx.x;
  if (e >= ET) return;
  int s, d;
  if (e < E_EDGES) { s = ei[e]; d = ei[E_EDGES + e]; }
  else { s = d = e - E_EDGES; }
  atomicAdd(&denom[d], __expf(lrelu(a_s[s] + a_d[d])));
}

// ---------------- aggregation (scatter-add) ----------------
__global__ __launch_bounds__(256) void agg1_kernel(const int* __restrict__ ei,
                                                   const float* __restrict__ a_s,
                                                   const float* __restrict__ a_d,
                                                   const float* __restrict__ denom,
                                                   const float* __restrict__ h1,
                                                   float* __restrict__ out1) {
  int gid = blockIdx.x * 256 + threadIdx.x;   // ET * 32 threads
  int e = gid >> 5, j = gid & 31;             // j: float4 chunk (4 feats)
  if (e >= ET) return;
  int s, d;
  if (e < E_EDGES) { s = ei[e]; d = ei[E_EDGES + e]; }
  else { s = d = e - E_EDGES; }
  int h = j >> 2;                              // head = (4j)/16
  float w = __expf(lrelu(a_s[(size_t)s * HEADS1 + h] + a_d[(size_t)d * HEADS1 + h]));
  float alpha = w / (denom[(size_t)d * HEADS1 + h] + 1e-16f);
  float4 hv = *(const float4*)&h1[(size_t)s * HID + 4 * j];
  float* o = &out1[(size_t)d * HID + 4 * j];
  atomicAdd(o + 0, alpha * hv.x);
  atomicAdd(o + 1, alpha * hv.y);
  atomicAdd(o + 2, alpha * hv.z);
  atomicAdd(o + 3, alpha * hv.w);
}

__global__ __launch_bounds__(256) void agg2_kernel(const int* __restrict__ ei,
                                                   const float* __restrict__ a_s,
                                                   const float* __restrict__ a_d,
                                                   const float* __restrict__ denom,
                                                   const float* __restrict__ h2,
                                                   float* __restrict__ out2) {
  int gid = blockIdx.x * 256 + threadIdx.x;   // ET * 16 threads
  int e = gid >> 4, j = gid & 15;
  if (e >= ET) return;
  int s, d;
  if (e < E_EDGES) { s = ei[e]; d = ei[E_EDGES + e]; }
  else { s = d = e - E_EDGES; }
  float w = __expf(lrelu(a_s[s] + a_d[d]));
  float alpha = w / (denom[d] + 1e-16f);
  float4 hv = *(const float4*)&h2[(size_t)s * OUT_F + 4 * j];
  float* o = &out2[(size_t)d * OUT_F + 4 * j];
  atomicAdd(o + 0, alpha * hv.x);
  atomicAdd(o + 1, alpha * hv.y);
  atomicAdd(o + 2, alpha * hv.z);
  atomicAdd(o + 3, alpha * hv.w);
}

// ---------------- elementwise: out1 = elu(out1 + b1) ----------------
__global__ __launch_bounds__(256) void elu_kernel(float* __restrict__ out1,
                                                  const float* __restrict__ b1) {
  int gid = blockIdx.x * 256 + threadIdx.x;   // N*HID/4 threads
  float4 v = ((float4*)out1)[gid];
  int c = (gid * 4) & (HID - 1);
  v.x += b1[c + 0]; v.y += b1[c + 1]; v.z += b1[c + 2]; v.w += b1[c + 3];
  v.x = v.x > 0.f ? v.x : expm1f(v.x);
  v.y = v.y > 0.f ? v.y : expm1f(v.y);
  v.z = v.z > 0.f ? v.z : expm1f(v.z);
  v.w = v.w > 0.f ? v.w : expm1f(v.w);
  ((float4*)out1)[gid] = v;
}

// ---------------- final: log_softmax rows ----------------
__global__ __launch_bounds__(256) void logsm_kernel(const float* __restrict__ out2,
                                                    const float* __restrict__ b2,
                                                    float* __restrict__ out) {
  int wid = (blockIdx.x * 256 + threadIdx.x) >> 6;  // node per wave
  int lane = threadIdx.x & 63;
  if (wid >= N_NODES) return;
  float v = out2[(size_t)wid * OUT_F + lane] + b2[lane];
  float m = v;
#pragma unroll
  for (int msk = 1; msk < 64; msk <<= 1) m = fmaxf(m, __shfl_xor(m, msk));
  float s = __expf(v - m);
#pragma unroll
  for (int msk = 1; msk < 64; msk <<= 1) s += __shfl_xor(s, msk);
  out[(size_t)wid * OUT_F + lane] = v - m - __logf(s);
}

extern "C" void kernel_launch(void* const* d_in, const int* in_sizes, int n_in,
                              void* d_out, int out_size, void* d_ws, size_t ws_size,
                              hipStream_t stream) {
  const float* x   = (const float*)d_in[0];
  const int* ei    = (const int*)d_in[1];
  const float* W1  = (const float*)d_in[2];
  const float* as1 = (const float*)d_in[3];
  const float* ad1 = (const float*)d_in[4];
  const float* b1  = (const float*)d_in[5];
  const float* W2  = (const float*)d_in[6];
  const float* as2 = (const float*)d_in[7];
  const float* ad2 = (const float*)d_in[8];
  const float* b2  = (const float*)d_in[9];
  float* out = (float*)d_out;

  float* ws = (float*)d_ws;
  float* h1     = ws;  ws += (size_t)N_NODES * HID;       // 6.4M
  float* a_s1   = ws;  ws += (size_t)N_NODES * HEADS1;    // 0.4M
  float* a_d1   = ws;  ws += (size_t)N_NODES * HEADS1;
  float* denom1 = ws;  ws += (size_t)N_NODES * HEADS1;
  float* out1   = ws;  ws += (size_t)N_NODES * HID;       // 6.4M
  float* h2     = ws;  ws += (size_t)N_NODES * OUT_F;     // 3.2M
  float* a_s2   = ws;  ws += (size_t)N_NODES;
  float* a_d2   = ws;  ws += (size_t)N_NODES;
  float* denom2 = ws;  ws += (size_t)N_NODES;
  float* out2   = ws;  ws += (size_t)N_NODES * OUT_F;     // 3.2M

  // zero the accumulators (ws is re-poisoned before every call)
  hipMemsetAsync(denom1, 0, sizeof(float) * (size_t)N_NODES * HEADS1, stream);
  hipMemsetAsync(out1,   0, sizeof(float) * (size_t)N_NODES * HID,    stream);
  hipMemsetAsync(denom2, 0, sizeof(float) * (size_t)N_NODES,          stream);
  hipMemsetAsync(out2,   0, sizeof(float) * (size_t)N_NODES * OUT_F,  stream);

  // ---- layer 1 ----
  gemm1_kernel<<<dim3((N_NODES + 63) / 64), dim3(256), 0, stream>>>(x, W1, h1);
  att1_kernel<<<dim3((N_NODES * 64 + 255) / 256), dim3(256), 0, stream>>>(h1, as1, ad1, a_s1, a_d1);
  edge_denom1_kernel<<<dim3((ET + 255) / 256), dim3(256), 0, stream>>>(ei, a_s1, a_d1, denom1);
  agg1_kernel<<<dim3((ET * 32 + 255) / 256), dim3(256), 0, stream>>>(ei, a_s1, a_d1, denom1, h1, out1);
  elu_kernel<<<dim3(N_NODES * HID / 4 / 256), dim3(256), 0, stream>>>(out1, b1);

  // ---- layer 2 ----
  gemm2_kernel<<<dim3((N_NODES + 63) / 64), dim3(256), 0, stream>>>(out1, W2, h2);
  att2_kernel<<<dim3((N_NODES * 64 + 255) / 256), dim3(256), 0, stream>>>(h2, as2, ad2, a_s2, a_d2);
  edge_denom2_kernel<<<dim3((ET + 255) / 256), dim3(256), 0, stream>>>(ei, a_s2, a_d2, denom2);
  agg2_kernel<<<dim3((ET * 16 + 255) / 256), dim3(256), 0, stream>>>(ei, a_s2, a_d2, denom2, h2, out2);
  logsm_kernel<<<dim3((N_NODES * 64 + 255) / 256), dim3(256), 0, stream>>>(out2, b2, out);
}

// Round 2
// 589.044 us; speedup vs baseline: 4.7077x; 4.7077x over previous
//
#include <hip/hip_runtime.h>
#include <math.h>

#define N_NODES 50000
#define E_EDGES 800000
#define ET (E_EDGES + N_NODES)   // edges + self loops
#define IN_F 256
#define HID 128
#define HEADS1 8
#define C1 16
#define OUT_F 64
#define NEG_SLOPE 0.2f
#define SCAN_CHUNK 196           // 256*196 = 50176 >= 50000

__device__ __forceinline__ float lrelu(float v) { return v > 0.f ? v : NEG_SLOPE * v; }

// ---------------- GEMM1: h1[N,128] = x[N,256] @ W1[256,128] ----------------
__global__ __launch_bounds__(256) void gemm1_kernel(const float* __restrict__ x,
                                                    const float* __restrict__ W,
                                                    float* __restrict__ h1) {
  __shared__ float As[64][32];
  __shared__ float Bs[32][132];
  const int t = threadIdx.x;
  const int row0 = blockIdx.x * 64;
  const int rg = t >> 5;
  const int cg = t & 31;
  float acc[8][4];
#pragma unroll
  for (int i = 0; i < 8; ++i)
#pragma unroll
    for (int j = 0; j < 4; ++j) acc[i][j] = 0.f;

  const int ar = t >> 2;
  const int ak = (t & 3) * 8;
  const int arow = row0 + ar;
  const int bkk = t >> 3;
  const int bn = (t & 7) * 16;

  for (int k0 = 0; k0 < IN_F; k0 += 32) {
    float4 av0, av1;
    if (arow < N_NODES) {
      const float4* ap = (const float4*)&x[(size_t)arow * IN_F + k0 + ak];
      av0 = ap[0]; av1 = ap[1];
    } else {
      av0 = make_float4(0.f, 0.f, 0.f, 0.f); av1 = av0;
    }
    *(float4*)&As[ar][ak]     = av0;
    *(float4*)&As[ar][ak + 4] = av1;

    const float* wp = &W[(size_t)(k0 + bkk) * HID + bn];
    float4 bv0 = *(const float4*)(wp + 0);
    float4 bv1 = *(const float4*)(wp + 4);
    float4 bv2 = *(const float4*)(wp + 8);
    float4 bv3 = *(const float4*)(wp + 12);
    *(float4*)&Bs[bkk][bn + 0]  = bv0;
    *(float4*)&Bs[bkk][bn + 4]  = bv1;
    *(float4*)&Bs[bkk][bn + 8]  = bv2;
    *(float4*)&Bs[bkk][bn + 12] = bv3;
    __syncthreads();

#pragma unroll
    for (int kk = 0; kk < 32; kk += 4) {
      float b[4][4];
#pragma unroll
      for (int j = 0; j < 4; ++j) {
        float4 bb = *(const float4*)&Bs[kk + j][cg * 4];
        b[j][0] = bb.x; b[j][1] = bb.y; b[j][2] = bb.z; b[j][3] = bb.w;
      }
#pragma unroll
      for (int i = 0; i < 8; ++i) {
        float4 aa = *(const float4*)&As[8 * rg + i][kk];
#pragma unroll
        for (int j = 0; j < 4; ++j) {
          acc[i][j] += aa.x * b[0][j] + aa.y * b[1][j] + aa.z * b[2][j] + aa.w * b[3][j];
        }
      }
    }
    __syncthreads();
  }
#pragma unroll
  for (int i = 0; i < 8; ++i) {
    int row = row0 + 8 * rg + i;
    if (row < N_NODES) {
      float4 v = make_float4(acc[i][0], acc[i][1], acc[i][2], acc[i][3]);
      *(float4*)&h1[(size_t)row * HID + cg * 4] = v;
    }
  }
}

// ---------------- GEMM2: h2[N,64] = in[N,128] @ W2[128,64] ----------------
__global__ __launch_bounds__(256) void gemm2_kernel(const float* __restrict__ in,
                                                    const float* __restrict__ W,
                                                    float* __restrict__ h2) {
  __shared__ float As[64][32];
  __shared__ float Bs[32][68];
  const int t = threadIdx.x;
  const int row0 = blockIdx.x * 64;
  const int rg = t >> 4;
  const int cg = t & 15;
  float acc[4][4];
#pragma unroll
  for (int i = 0; i < 4; ++i)
#pragma unroll
    for (int j = 0; j < 4; ++j) acc[i][j] = 0.f;

  const int ar = t >> 2;
  const int ak = (t & 3) * 8;
  const int arow = row0 + ar;
  const int bkk = t >> 3;
  const int bn = (t & 7) * 8;

  for (int k0 = 0; k0 < HID; k0 += 32) {
    float4 av0, av1;
    if (arow < N_NODES) {
      const float4* ap = (const float4*)&in[(size_t)arow * HID + k0 + ak];
      av0 = ap[0]; av1 = ap[1];
    } else {
      av0 = make_float4(0.f, 0.f, 0.f, 0.f); av1 = av0;
    }
    *(float4*)&As[ar][ak]     = av0;
    *(float4*)&As[ar][ak + 4] = av1;

    const float* wp = &W[(size_t)(k0 + bkk) * OUT_F + bn];
    float4 bv0 = *(const float4*)(wp + 0);
    float4 bv1 = *(const float4*)(wp + 4);
    *(float4*)&Bs[bkk][bn + 0] = bv0;
    *(float4*)&Bs[bkk][bn + 4] = bv1;
    __syncthreads();

#pragma unroll
    for (int kk = 0; kk < 32; kk += 4) {
      float b[4][4];
#pragma unroll
      for (int j = 0; j < 4; ++j) {
        float4 bb = *(const float4*)&Bs[kk + j][cg * 4];
        b[j][0] = bb.x; b[j][1] = bb.y; b[j][2] = bb.z; b[j][3] = bb.w;
      }
#pragma unroll
      for (int i = 0; i < 4; ++i) {
        float4 aa = *(const float4*)&As[4 * rg + i][kk];
#pragma unroll
        for (int j = 0; j < 4; ++j) {
          acc[i][j] += aa.x * b[0][j] + aa.y * b[1][j] + aa.z * b[2][j] + aa.w * b[3][j];
        }
      }
    }
    __syncthreads();
  }
#pragma unroll
  for (int i = 0; i < 4; ++i) {
    int row = row0 + 4 * rg + i;
    if (row < N_NODES) {
      float4 v = make_float4(acc[i][0], acc[i][1], acc[i][2], acc[i][3]);
      *(float4*)&h2[(size_t)row * OUT_F + cg * 4] = v;
    }
  }
}

// ---------------- att1: a_s[N,8], a_d[N,8] from h1[N,128] ----------------
__global__ __launch_bounds__(256) void att1_kernel(const float* __restrict__ h1,
                                                   const float* __restrict__ att_src,
                                                   const float* __restrict__ att_dst,
                                                   float* __restrict__ a_s,
                                                   float* __restrict__ a_d) {
  int wid = (blockIdx.x * 256 + threadIdx.x) >> 6;
  int lane = threadIdx.x & 63;
  if (wid >= N_NODES) return;
  float2 h  = *(const float2*)&h1[(size_t)wid * HID + 2 * lane];
  float2 as = *(const float2*)&att_src[2 * lane];
  float2 ad = *(const float2*)&att_dst[2 * lane];
  float vs = h.x * as.x + h.y * as.y;
  float vd = h.x * ad.x + h.y * ad.y;
  vs += __shfl_xor(vs, 1); vd += __shfl_xor(vd, 1);
  vs += __shfl_xor(vs, 2); vd += __shfl_xor(vd, 2);
  vs += __shfl_xor(vs, 4); vd += __shfl_xor(vd, 4);
  if ((lane & 7) == 0) {
    a_s[wid * HEADS1 + (lane >> 3)] = vs;
    a_d[wid * HEADS1 + (lane >> 3)] = vd;
  }
}

// ---------------- att2: a_s[N], a_d[N] from h2[N,64] ----------------
__global__ __launch_bounds__(256) void att2_kernel(const float* __restrict__ h2,
                                                   const float* __restrict__ att_src,
                                                   const float* __restrict__ att_dst,
                                                   float* __restrict__ a_s,
                                                   float* __restrict__ a_d) {
  int wid = (blockIdx.x * 256 + threadIdx.x) >> 6;
  int lane = threadIdx.x & 63;
  if (wid >= N_NODES) return;
  float h = h2[(size_t)wid * OUT_F + lane];
  float vs = h * att_src[lane];
  float vd = h * att_dst[lane];
#pragma unroll
  for (int m = 1; m < 64; m <<= 1) { vs += __shfl_xor(vs, m); vd += __shfl_xor(vd, m); }
  if (lane == 0) { a_s[wid] = vs; a_d[wid] = vd; }
}

// ---------------- CSR construction ----------------
__global__ __launch_bounds__(256) void deg_kernel(const int* __restrict__ ei,
                                                  int* __restrict__ deg) {
  int e = blockIdx.x * 256 + threadIdx.x;
  if (e >= ET) return;
  int d = (e < E_EDGES) ? ei[E_EDGES + e] : (e - E_EDGES);
  atomicAdd(&deg[d], 1);
}

// single-block exclusive scan over deg[0..N), writes rowptr and cursor
__global__ __launch_bounds__(256) void scan_kernel(const int* __restrict__ deg,
                                                   int* __restrict__ rowptr,
                                                   int* __restrict__ cursor) {
  __shared__ int part[256];
  const int t = threadIdx.x;
  const int base = t * SCAN_CHUNK;
  int sum = 0;
  for (int i = 0; i < SCAN_CHUNK; ++i) {
    int idx = base + i;
    if (idx < N_NODES) sum += deg[idx];
  }
  part[t] = sum;
  __syncthreads();
  for (int off = 1; off < 256; off <<= 1) {
    int v = (t >= off) ? part[t - off] : 0;
    __syncthreads();
    part[t] += v;
    __syncthreads();
  }
  int run = (t == 0) ? 0 : part[t - 1];
  for (int i = 0; i < SCAN_CHUNK; ++i) {
    int idx = base + i;
    if (idx < N_NODES) {
      int d = deg[idx];
      rowptr[idx] = run;
      cursor[idx] = run;
      run += d;
    }
  }
  if (t == 255) rowptr[N_NODES] = run;   // == ET
}

__global__ __launch_bounds__(256) void scatter_kernel(const int* __restrict__ ei,
                                                      int* __restrict__ cursor,
                                                      int* __restrict__ csr_src) {
  int e = blockIdx.x * 256 + threadIdx.x;
  if (e >= ET) return;
  int s, d;
  if (e < E_EDGES) { s = ei[e]; d = ei[E_EDGES + e]; }
  else { s = d = e - E_EDGES; }
  int pos = atomicAdd(&cursor[d], 1);
  csr_src[pos] = s;
}

// ---------------- agg1: one wave per dst node; fused softmax-norm + bias + ELU ----
__global__ __launch_bounds__(256) void agg1_csr_kernel(const int* __restrict__ rowptr,
                                                       const int* __restrict__ csr_src,
                                                       const float* __restrict__ a_s,
                                                       const float* __restrict__ a_d,
                                                       const float* __restrict__ h1,
                                                       const float* __restrict__ b1,
                                                       float* __restrict__ out1) {
  int wid = (blockIdx.x * 256 + threadIdx.x) >> 6;   // dst node
  int lane = threadIdx.x & 63;                       // lane owns feats 2*lane, 2*lane+1
  if (wid >= N_NODES) return;
  const int head = lane >> 3;                        // 2*lane/16
  const float adn = a_d[(size_t)wid * HEADS1 + head];
  int i = rowptr[wid], end = rowptr[wid + 1];
  float ax = 0.f, ay = 0.f, wsum = 0.f;
  for (; i + 1 < end; i += 2) {
    int s0 = csr_src[i], s1 = csr_src[i + 1];
    float2 h0 = *(const float2*)&h1[(size_t)s0 * HID + 2 * lane];
    float2 h1v = *(const float2*)&h1[(size_t)s1 * HID + 2 * lane];
    float w0 = __expf(lrelu(a_s[(size_t)s0 * HEADS1 + head] + adn));
    float w1 = __expf(lrelu(a_s[(size_t)s1 * HEADS1 + head] + adn));
    ax += w0 * h0.x + w1 * h1v.x;
    ay += w0 * h0.y + w1 * h1v.y;
    wsum += w0 + w1;
  }
  if (i < end) {
    int s0 = csr_src[i];
    float2 h0 = *(const float2*)&h1[(size_t)s0 * HID + 2 * lane];
    float w0 = __expf(lrelu(a_s[(size_t)s0 * HEADS1 + head] + adn));
    ax += w0 * h0.x; ay += w0 * h0.y; wsum += w0;
  }
  float inv = 1.f / (wsum + 1e-16f);
  float vx = ax * inv + b1[2 * lane];
  float vy = ay * inv + b1[2 * lane + 1];
  vx = vx > 0.f ? vx : expm1f(vx);
  vy = vy > 0.f ? vy : expm1f(vy);
  float2 o; o.x = vx; o.y = vy;
  *(float2*)&out1[(size_t)wid * HID + 2 * lane] = o;
}

// ---------------- agg2: one wave per dst node; fused bias + log_softmax ----------
__global__ __launch_bounds__(256) void agg2_csr_kernel(const int* __restrict__ rowptr,
                                                       const int* __restrict__ csr_src,
                                                       const float* __restrict__ a_s,
                                                       const float* __restrict__ a_d,
                                                       const float* __restrict__ h2,
                                                       const float* __restrict__ b2,
                                                       float* __restrict__ out) {
  int wid = (blockIdx.x * 256 + threadIdx.x) >> 6;   // dst node
  int lane = threadIdx.x & 63;                       // lane owns feat `lane`
  if (wid >= N_NODES) return;
  const float adn = a_d[wid];
  int i = rowptr[wid], end = rowptr[wid + 1];
  float acc = 0.f, wsum = 0.f;
  for (; i + 1 < end; i += 2) {
    int s0 = csr_src[i], s1 = csr_src[i + 1];
    float h0 = h2[(size_t)s0 * OUT_F + lane];
    float h1v = h2[(size_t)s1 * OUT_F + lane];
    float w0 = __expf(lrelu(a_s[s0] + adn));
    float w1 = __expf(lrelu(a_s[s1] + adn));
    acc += w0 * h0 + w1 * h1v;
    wsum += w0 + w1;
  }
  if (i < end) {
    int s0 = csr_src[i];
    acc += __expf(lrelu(a_s[s0] + adn)) * h2[(size_t)s0 * OUT_F + lane];
    wsum += __expf(lrelu(a_s[s0] + adn));
  }
  float v = acc / (wsum + 1e-16f) + b2[lane];
  float m = v;
#pragma unroll
  for (int msk = 1; msk < 64; msk <<= 1) m = fmaxf(m, __shfl_xor(m, msk));
  float sm = __expf(v - m);
#pragma unroll
  for (int msk = 1; msk < 64; msk <<= 1) sm += __shfl_xor(sm, msk);
  out[(size_t)wid * OUT_F + lane] = v - m - __logf(sm);
}

extern "C" void kernel_launch(void* const* d_in, const int* in_sizes, int n_in,
                              void* d_out, int out_size, void* d_ws, size_t ws_size,
                              hipStream_t stream) {
  const float* x   = (const float*)d_in[0];
  const int* ei    = (const int*)d_in[1];
  const float* W1  = (const float*)d_in[2];
  const float* as1 = (const float*)d_in[3];
  const float* ad1 = (const float*)d_in[4];
  const float* b1  = (const float*)d_in[5];
  const float* W2  = (const float*)d_in[6];
  const float* as2 = (const float*)d_in[7];
  const float* ad2 = (const float*)d_in[8];
  const float* b2  = (const float*)d_in[9];
  float* out = (float*)d_out;

  float* ws = (float*)d_ws;
  float* h1     = ws;  ws += (size_t)N_NODES * HID;
  float* a_s1   = ws;  ws += (size_t)N_NODES * HEADS1;
  float* a_d1   = ws;  ws += (size_t)N_NODES * HEADS1;
  float* out1   = ws;  ws += (size_t)N_NODES * HID;
  float* h2     = ws;  ws += (size_t)N_NODES * OUT_F;
  float* a_s2   = ws;  ws += (size_t)N_NODES;
  float* a_d2   = ws;  ws += (size_t)N_NODES;
  int* deg      = (int*)ws;  ws += (N_NODES + 1);
  int* rowptr   = (int*)ws;  ws += (N_NODES + 1);
  int* cursor   = (int*)ws;  ws += N_NODES;
  int* csr_src  = (int*)ws;  ws += ET;

  // ---- CSR build (independent of GEMM1; scheduler can overlap) ----
  hipMemsetAsync(deg, 0, sizeof(int) * (N_NODES + 1), stream);
  deg_kernel<<<dim3((ET + 255) / 256), dim3(256), 0, stream>>>(ei, deg);
  scan_kernel<<<dim3(1), dim3(256), 0, stream>>>(deg, rowptr, cursor);
  scatter_kernel<<<dim3((ET + 255) / 256), dim3(256), 0, stream>>>(ei, cursor, csr_src);

  // ---- layer 1 ----
  gemm1_kernel<<<dim3((N_NODES + 63) / 64), dim3(256), 0, stream>>>(x, W1, h1);
  att1_kernel<<<dim3((N_NODES * 64 + 255) / 256), dim3(256), 0, stream>>>(h1, as1, ad1, a_s1, a_d1);
  agg1_csr_kernel<<<dim3((N_NODES + 3) / 4), dim3(256), 0, stream>>>(rowptr, csr_src, a_s1, a_d1, h1, b1, out1);

  // ---- layer 2 ----
  gemm2_kernel<<<dim3((N_NODES + 63) / 64), dim3(256), 0, stream>>>(out1, W2, h2);
  att2_kernel<<<dim3((N_NODES * 64 + 255) / 256), dim3(256), 0, stream>>>(h2, as2, ad2, a_s2, a_d2);
  agg2_csr_kernel<<<dim3((N_NODES + 3) / 4), dim3(256), 0, stream>>>(rowptr, csr_src, a_s2, a_d2, h2, b2, out);
}

// Round 3
// 459.707 us; speedup vs baseline: 6.0322x; 1.2813x over previous
//
#include <hip/hip_runtime.h>
#include <math.h>

#define N_NODES 50000
#define E_EDGES 800000
#define ET (E_EDGES + N_NODES)   // edges + self loops
#define IN_F 256
#define HID 128
#define HEADS1 8
#define C1 16
#define OUT_F 64
#define NEG_SLOPE 0.2f
#define NBLK ((N_NODES + 255) / 256)   // 196 scan blocks

__device__ __forceinline__ float lrelu(float v) { return v > 0.f ? v : NEG_SLOPE * v; }

// ---------------- GEMM1: h1[N,128] = x[N,256] @ W1[256,128] ----------------
__global__ __launch_bounds__(256) void gemm1_kernel(const float* __restrict__ x,
                                                    const float* __restrict__ W,
                                                    float* __restrict__ h1) {
  __shared__ float As[64][32];
  __shared__ float Bs[32][132];
  const int t = threadIdx.x;
  const int row0 = blockIdx.x * 64;
  const int rg = t >> 5;
  const int cg = t & 31;
  float acc[8][4];
#pragma unroll
  for (int i = 0; i < 8; ++i)
#pragma unroll
    for (int j = 0; j < 4; ++j) acc[i][j] = 0.f;

  const int ar = t >> 2;
  const int ak = (t & 3) * 8;
  const int arow = row0 + ar;
  const int bkk = t >> 3;
  const int bn = (t & 7) * 16;

  for (int k0 = 0; k0 < IN_F; k0 += 32) {
    float4 av0, av1;
    if (arow < N_NODES) {
      const float4* ap = (const float4*)&x[(size_t)arow * IN_F + k0 + ak];
      av0 = ap[0]; av1 = ap[1];
    } else {
      av0 = make_float4(0.f, 0.f, 0.f, 0.f); av1 = av0;
    }
    *(float4*)&As[ar][ak]     = av0;
    *(float4*)&As[ar][ak + 4] = av1;

    const float* wp = &W[(size_t)(k0 + bkk) * HID + bn];
    float4 bv0 = *(const float4*)(wp + 0);
    float4 bv1 = *(const float4*)(wp + 4);
    float4 bv2 = *(const float4*)(wp + 8);
    float4 bv3 = *(const float4*)(wp + 12);
    *(float4*)&Bs[bkk][bn + 0]  = bv0;
    *(float4*)&Bs[bkk][bn + 4]  = bv1;
    *(float4*)&Bs[bkk][bn + 8]  = bv2;
    *(float4*)&Bs[bkk][bn + 12] = bv3;
    __syncthreads();

#pragma unroll
    for (int kk = 0; kk < 32; kk += 4) {
      float b[4][4];
#pragma unroll
      for (int j = 0; j < 4; ++j) {
        float4 bb = *(const float4*)&Bs[kk + j][cg * 4];
        b[j][0] = bb.x; b[j][1] = bb.y; b[j][2] = bb.z; b[j][3] = bb.w;
      }
#pragma unroll
      for (int i = 0; i < 8; ++i) {
        float4 aa = *(const float4*)&As[8 * rg + i][kk];
#pragma unroll
        for (int j = 0; j < 4; ++j) {
          acc[i][j] += aa.x * b[0][j] + aa.y * b[1][j] + aa.z * b[2][j] + aa.w * b[3][j];
        }
      }
    }
    __syncthreads();
  }
#pragma unroll
  for (int i = 0; i < 8; ++i) {
    int row = row0 + 8 * rg + i;
    if (row < N_NODES) {
      float4 v = make_float4(acc[i][0], acc[i][1], acc[i][2], acc[i][3]);
      *(float4*)&h1[(size_t)row * HID + cg * 4] = v;
    }
  }
}

// ---------------- GEMM2: h2[N,64] = in[N,128] @ W2[128,64] ----------------
__global__ __launch_bounds__(256) void gemm2_kernel(const float* __restrict__ in,
                                                    const float* __restrict__ W,
                                                    float* __restrict__ h2) {
  __shared__ float As[64][32];
  __shared__ float Bs[32][68];
  const int t = threadIdx.x;
  const int row0 = blockIdx.x * 64;
  const int rg = t >> 4;
  const int cg = t & 15;
  float acc[4][4];
#pragma unroll
  for (int i = 0; i < 4; ++i)
#pragma unroll
    for (int j = 0; j < 4; ++j) acc[i][j] = 0.f;

  const int ar = t >> 2;
  const int ak = (t & 3) * 8;
  const int arow = row0 + ar;
  const int bkk = t >> 3;
  const int bn = (t & 7) * 8;

  for (int k0 = 0; k0 < HID; k0 += 32) {
    float4 av0, av1;
    if (arow < N_NODES) {
      const float4* ap = (const float4*)&in[(size_t)arow * HID + k0 + ak];
      av0 = ap[0]; av1 = ap[1];
    } else {
      av0 = make_float4(0.f, 0.f, 0.f, 0.f); av1 = av0;
    }
    *(float4*)&As[ar][ak]     = av0;
    *(float4*)&As[ar][ak + 4] = av1;

    const float* wp = &W[(size_t)(k0 + bkk) * OUT_F + bn];
    float4 bv0 = *(const float4*)(wp + 0);
    float4 bv1 = *(const float4*)(wp + 4);
    *(float4*)&Bs[bkk][bn + 0] = bv0;
    *(float4*)&Bs[bkk][bn + 4] = bv1;
    __syncthreads();

#pragma unroll
    for (int kk = 0; kk < 32; kk += 4) {
      float b[4][4];
#pragma unroll
      for (int j = 0; j < 4; ++j) {
        float4 bb = *(const float4*)&Bs[kk + j][cg * 4];
        b[j][0] = bb.x; b[j][1] = bb.y; b[j][2] = bb.z; b[j][3] = bb.w;
      }
#pragma unroll
      for (int i = 0; i < 4; ++i) {
        float4 aa = *(const float4*)&As[4 * rg + i][kk];
#pragma unroll
        for (int j = 0; j < 4; ++j) {
          acc[i][j] += aa.x * b[0][j] + aa.y * b[1][j] + aa.z * b[2][j] + aa.w * b[3][j];
        }
      }
    }
    __syncthreads();
  }
#pragma unroll
  for (int i = 0; i < 4; ++i) {
    int row = row0 + 4 * rg + i;
    if (row < N_NODES) {
      float4 v = make_float4(acc[i][0], acc[i][1], acc[i][2], acc[i][3]);
      *(float4*)&h2[(size_t)row * OUT_F + cg * 4] = v;
    }
  }
}

// ---------------- att1: a_s[N,8], a_d[N,8] from h1[N,128] ----------------
__global__ __launch_bounds__(256) void att1_kernel(const float* __restrict__ h1,
                                                   const float* __restrict__ att_src,
                                                   const float* __restrict__ att_dst,
                                                   float* __restrict__ a_s,
                                                   float* __restrict__ a_d) {
  int wid = (blockIdx.x * 256 + threadIdx.x) >> 6;
  int lane = threadIdx.x & 63;
  if (wid >= N_NODES) return;
  float2 h  = *(const float2*)&h1[(size_t)wid * HID + 2 * lane];
  float2 as = *(const float2*)&att_src[2 * lane];
  float2 ad = *(const float2*)&att_dst[2 * lane];
  float vs = h.x * as.x + h.y * as.y;
  float vd = h.x * ad.x + h.y * ad.y;
  vs += __shfl_xor(vs, 1); vd += __shfl_xor(vd, 1);
  vs += __shfl_xor(vs, 2); vd += __shfl_xor(vd, 2);
  vs += __shfl_xor(vs, 4); vd += __shfl_xor(vd, 4);
  if ((lane & 7) == 0) {
    a_s[wid * HEADS1 + (lane >> 3)] = vs;
    a_d[wid * HEADS1 + (lane >> 3)] = vd;
  }
}

// ---------------- att2: a_s[N], a_d[N] from h2[N,64] ----------------
__global__ __launch_bounds__(256) void att2_kernel(const float* __restrict__ h2,
                                                   const float* __restrict__ att_src,
                                                   const float* __restrict__ att_dst,
                                                   float* __restrict__ a_s,
                                                   float* __restrict__ a_d) {
  int wid = (blockIdx.x * 256 + threadIdx.x) >> 6;
  int lane = threadIdx.x & 63;
  if (wid >= N_NODES) return;
  float h = h2[(size_t)wid * OUT_F + lane];
  float vs = h * att_src[lane];
  float vd = h * att_dst[lane];
#pragma unroll
  for (int m = 1; m < 64; m <<= 1) { vs += __shfl_xor(vs, m); vd += __shfl_xor(vd, m); }
  if (lane == 0) { a_s[wid] = vs; a_d[wid] = vd; }
}

// ---------------- CSR construction ----------------
__global__ __launch_bounds__(256) void deg_kernel(const int* __restrict__ ei,
                                                  int* __restrict__ deg) {
  int e = blockIdx.x * 256 + threadIdx.x;
  if (e >= ET) return;
  int d = (e < E_EDGES) ? ei[E_EDGES + e] : (e - E_EDGES);
  atomicAdd(&deg[d], 1);
}

// hierarchical scan stage 1: per-block exclusive scan of 256-elem slices
__global__ __launch_bounds__(256) void scan1_kernel(const int* __restrict__ deg,
                                                    int* __restrict__ exq,
                                                    int* __restrict__ bsum) {
  __shared__ int sh[256];
  const int t = threadIdx.x;
  const int idx = blockIdx.x * 256 + t;
  int v = (idx < N_NODES) ? deg[idx] : 0;
  sh[t] = v;
  __syncthreads();
  for (int off = 1; off < 256; off <<= 1) {
    int u = (t >= off) ? sh[t - off] : 0;
    __syncthreads();
    sh[t] += u;
    __syncthreads();
  }
  if (idx < N_NODES) exq[idx] = sh[t] - v;   // exclusive within block
  if (t == 255) bsum[blockIdx.x] = sh[t];    // block total
}

// stage 2: single-block scan of the 196 block totals -> exclusive offsets
__global__ __launch_bounds__(256) void scan2_kernel(const int* __restrict__ bsum,
                                                    int* __restrict__ boff) {
  __shared__ int sh[256];
  const int t = threadIdx.x;
  int v = (t < NBLK) ? bsum[t] : 0;
  sh[t] = v;
  __syncthreads();
  for (int off = 1; off < 256; off <<= 1) {
    int u = (t >= off) ? sh[t - off] : 0;
    __syncthreads();
    sh[t] += u;
    __syncthreads();
  }
  if (t < NBLK) boff[t] = sh[t] - v;
}

// stage 3: combine -> rowptr, cursor
__global__ __launch_bounds__(256) void scan3_kernel(const int* __restrict__ exq,
                                                    const int* __restrict__ boff,
                                                    int* __restrict__ rowptr,
                                                    int* __restrict__ cursor) {
  const int idx = blockIdx.x * 256 + threadIdx.x;
  if (idx < N_NODES) {
    int r = exq[idx] + boff[blockIdx.x];
    rowptr[idx] = r;
    cursor[idx] = r;
  }
  if (idx == 0) rowptr[N_NODES] = ET;   // grand total is static
}

__global__ __launch_bounds__(256) void scatter_kernel(const int* __restrict__ ei,
                                                      int* __restrict__ cursor,
                                                      int* __restrict__ csr_src) {
  int e = blockIdx.x * 256 + threadIdx.x;
  if (e >= ET) return;
  int s, d;
  if (e < E_EDGES) { s = ei[e]; d = ei[E_EDGES + e]; }
  else { s = d = e - E_EDGES; }
  int pos = atomicAdd(&cursor[d], 1);
  csr_src[pos] = s;
}

// ---------------- agg1: one wave per dst node; fused softmax-norm + bias + ELU ----
__global__ __launch_bounds__(256) void agg1_csr_kernel(const int* __restrict__ rowptr,
                                                       const int* __restrict__ csr_src,
                                                       const float* __restrict__ a_s,
                                                       const float* __restrict__ a_d,
                                                       const float* __restrict__ h1,
                                                       const float* __restrict__ b1,
                                                       float* __restrict__ out1) {
  int wid = (blockIdx.x * 256 + threadIdx.x) >> 6;   // dst node
  int lane = threadIdx.x & 63;                       // lane owns feats 2*lane, 2*lane+1
  if (wid >= N_NODES) return;
  const int head = lane >> 3;                        // 2*lane/16
  const float adn = a_d[(size_t)wid * HEADS1 + head];
  int i = rowptr[wid], end = rowptr[wid + 1];
  float ax = 0.f, ay = 0.f, wsum = 0.f;
  for (; i + 1 < end; i += 2) {
    int s0 = csr_src[i], s1 = csr_src[i + 1];
    float2 h0 = *(const float2*)&h1[(size_t)s0 * HID + 2 * lane];
    float2 h1v = *(const float2*)&h1[(size_t)s1 * HID + 2 * lane];
    float w0 = __expf(lrelu(a_s[(size_t)s0 * HEADS1 + head] + adn));
    float w1 = __expf(lrelu(a_s[(size_t)s1 * HEADS1 + head] + adn));
    ax += w0 * h0.x + w1 * h1v.x;
    ay += w0 * h0.y + w1 * h1v.y;
    wsum += w0 + w1;
  }
  if (i < end) {
    int s0 = csr_src[i];
    float2 h0 = *(const float2*)&h1[(size_t)s0 * HID + 2 * lane];
    float w0 = __expf(lrelu(a_s[(size_t)s0 * HEADS1 + head] + adn));
    ax += w0 * h0.x; ay += w0 * h0.y; wsum += w0;
  }
  float inv = 1.f / (wsum + 1e-16f);
  float vx = ax * inv + b1[2 * lane];
  float vy = ay * inv + b1[2 * lane + 1];
  vx = vx > 0.f ? vx : expm1f(vx);
  vy = vy > 0.f ? vy : expm1f(vy);
  float2 o; o.x = vx; o.y = vy;
  *(float2*)&out1[(size_t)wid * HID + 2 * lane] = o;
}

// ---------------- agg2: one wave per dst node; fused bias + log_softmax ----------
__global__ __launch_bounds__(256) void agg2_csr_kernel(const int* __restrict__ rowptr,
                                                       const int* __restrict__ csr_src,
                                                       const float* __restrict__ a_s,
                                                       const float* __restrict__ a_d,
                                                       const float* __restrict__ h2,
                                                       const float* __restrict__ b2,
                                                       float* __restrict__ out) {
  int wid = (blockIdx.x * 256 + threadIdx.x) >> 6;   // dst node
  int lane = threadIdx.x & 63;                       // lane owns feat `lane`
  if (wid >= N_NODES) return;
  const float adn = a_d[wid];
  int i = rowptr[wid], end = rowptr[wid + 1];
  float acc = 0.f, wsum = 0.f;
  for (; i + 1 < end; i += 2) {
    int s0 = csr_src[i], s1 = csr_src[i + 1];
    float h0 = h2[(size_t)s0 * OUT_F + lane];
    float h1v = h2[(size_t)s1 * OUT_F + lane];
    float w0 = __expf(lrelu(a_s[s0] + adn));
    float w1 = __expf(lrelu(a_s[s1] + adn));
    acc += w0 * h0 + w1 * h1v;
    wsum += w0 + w1;
  }
  if (i < end) {
    int s0 = csr_src[i];
    acc += __expf(lrelu(a_s[s0] + adn)) * h2[(size_t)s0 * OUT_F + lane];
    wsum += __expf(lrelu(a_s[s0] + adn));
  }
  float v = acc / (wsum + 1e-16f) + b2[lane];
  float m = v;
#pragma unroll
  for (int msk = 1; msk < 64; msk <<= 1) m = fmaxf(m, __shfl_xor(m, msk));
  float sm = __expf(v - m);
#pragma unroll
  for (int msk = 1; msk < 64; msk <<= 1) sm += __shfl_xor(sm, msk);
  out[(size_t)wid * OUT_F + lane] = v - m - __logf(sm);
}

extern "C" void kernel_launch(void* const* d_in, const int* in_sizes, int n_in,
                              void* d_out, int out_size, void* d_ws, size_t ws_size,
                              hipStream_t stream) {
  const float* x   = (const float*)d_in[0];
  const int* ei    = (const int*)d_in[1];
  const float* W1  = (const float*)d_in[2];
  const float* as1 = (const float*)d_in[3];
  const float* ad1 = (const float*)d_in[4];
  const float* b1  = (const float*)d_in[5];
  const float* W2  = (const float*)d_in[6];
  const float* as2 = (const float*)d_in[7];
  const float* ad2 = (const float*)d_in[8];
  const float* b2  = (const float*)d_in[9];
  float* out = (float*)d_out;

  float* ws = (float*)d_ws;
  float* h1     = ws;  ws += (size_t)N_NODES * HID;
  float* a_s1   = ws;  ws += (size_t)N_NODES * HEADS1;
  float* a_d1   = ws;  ws += (size_t)N_NODES * HEADS1;
  float* out1   = ws;  ws += (size_t)N_NODES * HID;
  float* h2     = ws;  ws += (size_t)N_NODES * OUT_F;
  float* a_s2   = ws;  ws += (size_t)N_NODES;
  float* a_d2   = ws;  ws += (size_t)N_NODES;
  int* deg      = (int*)ws;  ws += (N_NODES + 1);
  int* rowptr   = (int*)ws;  ws += (N_NODES + 1);
  int* cursor   = (int*)ws;  ws += N_NODES;
  int* csr_src  = (int*)ws;  ws += ET;
  int* exq      = (int*)ws;  ws += N_NODES;
  int* bsum     = (int*)ws;  ws += NBLK;
  int* boff     = (int*)ws;  ws += NBLK;

  // ---- CSR build ----
  hipMemsetAsync(deg, 0, sizeof(int) * (N_NODES + 1), stream);
  deg_kernel<<<dim3((ET + 255) / 256), dim3(256), 0, stream>>>(ei, deg);
  scan1_kernel<<<dim3(NBLK), dim3(256), 0, stream>>>(deg, exq, bsum);
  scan2_kernel<<<dim3(1), dim3(256), 0, stream>>>(bsum, boff);
  scan3_kernel<<<dim3(NBLK), dim3(256), 0, stream>>>(exq, boff, rowptr, cursor);
  scatter_kernel<<<dim3((ET + 255) / 256), dim3(256), 0, stream>>>(ei, cursor, csr_src);

  // ---- layer 1 ----
  gemm1_kernel<<<dim3((N_NODES + 63) / 64), dim3(256), 0, stream>>>(x, W1, h1);
  att1_kernel<<<dim3((N_NODES * 64 + 255) / 256), dim3(256), 0, stream>>>(h1, as1, ad1, a_s1, a_d1);
  agg1_csr_kernel<<<dim3((N_NODES + 3) / 4), dim3(256), 0, stream>>>(rowptr, csr_src, a_s1, a_d1, h1, b1, out1);

  // ---- layer 2 ----
  gemm2_kernel<<<dim3((N_NODES + 63) / 64), dim3(256), 0, stream>>>(out1, W2, h2);
  att2_kernel<<<dim3((N_NODES * 64 + 255) / 256), dim3(256), 0, stream>>>(h2, as2, ad2, a_s2, a_d2);
  agg2_csr_kernel<<<dim3((N_NODES + 3) / 4), dim3(256), 0, stream>>>(rowptr, csr_src, a_s2, a_d2, h2, b2, out);
}

// Round 4
// 400.629 us; speedup vs baseline: 6.9217x; 1.1475x over previous
//
#include <hip/hip_runtime.h>
#include <math.h>

#define N_NODES 50000
#define E_EDGES 800000
#define ET (E_EDGES + N_NODES)   // edges + self loops
#define IN_F 256
#define HID 128
#define HEADS1 8
#define C1 16
#define OUT_F 64
#define NEG_SLOPE 0.2f
#define NBLK ((N_NODES + 255) / 256)   // 196 scan blocks

typedef __attribute__((ext_vector_type(8))) short short8;
typedef __attribute__((ext_vector_type(4))) float float4v;

__device__ __forceinline__ float lrelu(float v) { return v > 0.f ? v : NEG_SLOPE * v; }

__device__ __forceinline__ short f2bf(float f) {
  union { float f; unsigned u; } v; v.f = f;
  unsigned r = v.u + 0x7FFF + ((v.u >> 16) & 1);   // RNE
  return (short)(r >> 16);
}

// ---- W transpose+cast: Wt[n][k] bf16 from W[k][n] fp32 ----
__global__ __launch_bounds__(256) void wt_kernel(const float* __restrict__ W,
                                                 unsigned short* __restrict__ Wt,
                                                 int K, int Nc) {
  int i = blockIdx.x * 256 + threadIdx.x;
  if (i >= K * Nc) return;
  int n = i / K, k = i - n * K;
  Wt[i] = (unsigned short)f2bf(W[k * Nc + n]);
}

// ---------------- GEMM1 (MFMA): h1[N,128] = x[N,256] @ W1[256,128] ----------------
// One wave per 16 output rows; A loaded fp32->bf16 in-register; B from W1t (L2-hot).
__global__ __launch_bounds__(256) void gemm1_mfma_kernel(const float* __restrict__ x,
                                                         const unsigned short* __restrict__ W1t,
                                                         float* __restrict__ h1) {
  const int wave = blockIdx.x * 4 + (threadIdx.x >> 6);
  const int lane = threadIdx.x & 63;
  const int m0 = wave * 16;
  if (m0 >= N_NODES) return;
  const int lm = lane & 15;        // row within tile (A), col within tile (B, C/D)
  const int quad = lane >> 4;      // k-quad (A/B), row-quad (C/D)
  const int mrow = m0 + lm;
  const bool valid = mrow < N_NODES;
  const float* arow = x + (size_t)mrow * IN_F;

  float4v acc[8];
#pragma unroll
  for (int nt = 0; nt < 8; ++nt) acc[nt] = (float4v){0.f, 0.f, 0.f, 0.f};

#pragma unroll
  for (int k0 = 0; k0 < IN_F; k0 += 32) {
    short8 a;
    if (valid) {
      float4 f0 = *(const float4*)(arow + k0 + quad * 8);
      float4 f1 = *(const float4*)(arow + k0 + quad * 8 + 4);
      a[0] = f2bf(f0.x); a[1] = f2bf(f0.y); a[2] = f2bf(f0.z); a[3] = f2bf(f0.w);
      a[4] = f2bf(f1.x); a[5] = f2bf(f1.y); a[6] = f2bf(f1.z); a[7] = f2bf(f1.w);
    } else {
      a = (short8){0, 0, 0, 0, 0, 0, 0, 0};
    }
#pragma unroll
    for (int nt = 0; nt < 8; ++nt) {
      short8 b = *(const short8*)&W1t[(size_t)(nt * 16 + lm) * IN_F + k0 + quad * 8];
      acc[nt] = __builtin_amdgcn_mfma_f32_16x16x32_bf16(a, b, acc[nt], 0, 0, 0);
    }
  }

#pragma unroll
  for (int nt = 0; nt < 8; ++nt) {
#pragma unroll
    for (int r = 0; r < 4; ++r) {
      int row = m0 + quad * 4 + r;
      if (row < N_NODES) h1[(size_t)row * HID + nt * 16 + lm] = acc[nt][r];
    }
  }
}

// ---------------- GEMM2 (MFMA): h2[N,64] = out1[N,128] @ W2[128,64] ----------------
__global__ __launch_bounds__(256) void gemm2_mfma_kernel(const float* __restrict__ in,
                                                         const unsigned short* __restrict__ W2t,
                                                         float* __restrict__ h2) {
  const int wave = blockIdx.x * 4 + (threadIdx.x >> 6);
  const int lane = threadIdx.x & 63;
  const int m0 = wave * 16;
  if (m0 >= N_NODES) return;
  const int lm = lane & 15;
  const int quad = lane >> 4;
  const int mrow = m0 + lm;
  const bool valid = mrow < N_NODES;
  const float* arow = in + (size_t)mrow * HID;

  float4v acc[4];
#pragma unroll
  for (int nt = 0; nt < 4; ++nt) acc[nt] = (float4v){0.f, 0.f, 0.f, 0.f};

#pragma unroll
  for (int k0 = 0; k0 < HID; k0 += 32) {
    short8 a;
    if (valid) {
      float4 f0 = *(const float4*)(arow + k0 + quad * 8);
      float4 f1 = *(const float4*)(arow + k0 + quad * 8 + 4);
      a[0] = f2bf(f0.x); a[1] = f2bf(f0.y); a[2] = f2bf(f0.z); a[3] = f2bf(f0.w);
      a[4] = f2bf(f1.x); a[5] = f2bf(f1.y); a[6] = f2bf(f1.z); a[7] = f2bf(f1.w);
    } else {
      a = (short8){0, 0, 0, 0, 0, 0, 0, 0};
    }
#pragma unroll
    for (int nt = 0; nt < 4; ++nt) {
      short8 b = *(const short8*)&W2t[(size_t)(nt * 16 + lm) * HID + k0 + quad * 8];
      acc[nt] = __builtin_amdgcn_mfma_f32_16x16x32_bf16(a, b, acc[nt], 0, 0, 0);
    }
  }

#pragma unroll
  for (int nt = 0; nt < 4; ++nt) {
#pragma unroll
    for (int r = 0; r < 4; ++r) {
      int row = m0 + quad * 4 + r;
      if (row < N_NODES) h2[(size_t)row * OUT_F + nt * 16 + lm] = acc[nt][r];
    }
  }
}

// ---------------- att1: a_s[N,8], a_d[N,8] from h1[N,128] ----------------
__global__ __launch_bounds__(256) void att1_kernel(const float* __restrict__ h1,
                                                   const float* __restrict__ att_src,
                                                   const float* __restrict__ att_dst,
                                                   float* __restrict__ a_s,
                                                   float* __restrict__ a_d) {
  int wid = (blockIdx.x * 256 + threadIdx.x) >> 6;
  int lane = threadIdx.x & 63;
  if (wid >= N_NODES) return;
  float2 h  = *(const float2*)&h1[(size_t)wid * HID + 2 * lane];
  float2 as = *(const float2*)&att_src[2 * lane];
  float2 ad = *(const float2*)&att_dst[2 * lane];
  float vs = h.x * as.x + h.y * as.y;
  float vd = h.x * ad.x + h.y * ad.y;
  vs += __shfl_xor(vs, 1); vd += __shfl_xor(vd, 1);
  vs += __shfl_xor(vs, 2); vd += __shfl_xor(vd, 2);
  vs += __shfl_xor(vs, 4); vd += __shfl_xor(vd, 4);
  if ((lane & 7) == 0) {
    a_s[wid * HEADS1 + (lane >> 3)] = vs;
    a_d[wid * HEADS1 + (lane >> 3)] = vd;
  }
}

// ---------------- att2: a_s[N], a_d[N] from h2[N,64] ----------------
__global__ __launch_bounds__(256) void att2_kernel(const float* __restrict__ h2,
                                                   const float* __restrict__ att_src,
                                                   const float* __restrict__ att_dst,
                                                   float* __restrict__ a_s,
                                                   float* __restrict__ a_d) {
  int wid = (blockIdx.x * 256 + threadIdx.x) >> 6;
  int lane = threadIdx.x & 63;
  if (wid >= N_NODES) return;
  float h = h2[(size_t)wid * OUT_F + lane];
  float vs = h * att_src[lane];
  float vd = h * att_dst[lane];
#pragma unroll
  for (int m = 1; m < 64; m <<= 1) { vs += __shfl_xor(vs, m); vd += __shfl_xor(vd, m); }
  if (lane == 0) { a_s[wid] = vs; a_d[wid] = vd; }
}

// ---------------- CSR construction ----------------
__global__ __launch_bounds__(256) void deg_kernel(const int* __restrict__ ei,
                                                  int* __restrict__ deg) {
  int e = blockIdx.x * 256 + threadIdx.x;
  if (e >= ET) return;
  int d = (e < E_EDGES) ? ei[E_EDGES + e] : (e - E_EDGES);
  atomicAdd(&deg[d], 1);
}

__global__ __launch_bounds__(256) void scan1_kernel(const int* __restrict__ deg,
                                                    int* __restrict__ exq,
                                                    int* __restrict__ bsum) {
  __shared__ int sh[256];
  const int t = threadIdx.x;
  const int idx = blockIdx.x * 256 + t;
  int v = (idx < N_NODES) ? deg[idx] : 0;
  sh[t] = v;
  __syncthreads();
  for (int off = 1; off < 256; off <<= 1) {
    int u = (t >= off) ? sh[t - off] : 0;
    __syncthreads();
    sh[t] += u;
    __syncthreads();
  }
  if (idx < N_NODES) exq[idx] = sh[t] - v;
  if (t == 255) bsum[blockIdx.x] = sh[t];
}

__global__ __launch_bounds__(256) void scan2_kernel(const int* __restrict__ bsum,
                                                    int* __restrict__ boff) {
  __shared__ int sh[256];
  const int t = threadIdx.x;
  int v = (t < NBLK) ? bsum[t] : 0;
  sh[t] = v;
  __syncthreads();
  for (int off = 1; off < 256; off <<= 1) {
    int u = (t >= off) ? sh[t - off] : 0;
    __syncthreads();
    sh[t] += u;
    __syncthreads();
  }
  if (t < NBLK) boff[t] = sh[t] - v;
}

__global__ __launch_bounds__(256) void scan3_kernel(const int* __restrict__ exq,
                                                    const int* __restrict__ boff,
                                                    int* __restrict__ rowptr,
                                                    int* __restrict__ cursor) {
  const int idx = blockIdx.x * 256 + threadIdx.x;
  if (idx < N_NODES) {
    int r = exq[idx] + boff[blockIdx.x];
    rowptr[idx] = r;
    cursor[idx] = r;
  }
  if (idx == 0) rowptr[N_NODES] = ET;
}

__global__ __launch_bounds__(256) void scatter_kernel(const int* __restrict__ ei,
                                                      int* __restrict__ cursor,
                                                      int* __restrict__ csr_src) {
  int e = blockIdx.x * 256 + threadIdx.x;
  if (e >= ET) return;
  int s, d;
  if (e < E_EDGES) { s = ei[e]; d = ei[E_EDGES + e]; }
  else { s = d = e - E_EDGES; }
  int pos = atomicAdd(&cursor[d], 1);
  csr_src[pos] = s;
}

// ---------------- agg1: one wave per dst node; fused softmax-norm + bias + ELU ----
__global__ __launch_bounds__(256) void agg1_csr_kernel(const int* __restrict__ rowptr,
                                                       const int* __restrict__ csr_src,
                                                       const float* __restrict__ a_s,
                                                       const float* __restrict__ a_d,
                                                       const float* __restrict__ h1,
                                                       const float* __restrict__ b1,
                                                       float* __restrict__ out1) {
  int wid = (blockIdx.x * 256 + threadIdx.x) >> 6;
  int lane = threadIdx.x & 63;
  if (wid >= N_NODES) return;
  const int head = lane >> 3;
  const float adn = a_d[(size_t)wid * HEADS1 + head];
  int i = rowptr[wid], end = rowptr[wid + 1];
  float ax = 0.f, ay = 0.f, wsum = 0.f;
  for (; i + 1 < end; i += 2) {
    int s0 = csr_src[i], s1 = csr_src[i + 1];
    float2 h0 = *(const float2*)&h1[(size_t)s0 * HID + 2 * lane];
    float2 h1v = *(const float2*)&h1[(size_t)s1 * HID + 2 * lane];
    float w0 = __expf(lrelu(a_s[(size_t)s0 * HEADS1 + head] + adn));
    float w1 = __expf(lrelu(a_s[(size_t)s1 * HEADS1 + head] + adn));
    ax += w0 * h0.x + w1 * h1v.x;
    ay += w0 * h0.y + w1 * h1v.y;
    wsum += w0 + w1;
  }
  if (i < end) {
    int s0 = csr_src[i];
    float2 h0 = *(const float2*)&h1[(size_t)s0 * HID + 2 * lane];
    float w0 = __expf(lrelu(a_s[(size_t)s0 * HEADS1 + head] + adn));
    ax += w0 * h0.x; ay += w0 * h0.y; wsum += w0;
  }
  float inv = 1.f / (wsum + 1e-16f);
  float vx = ax * inv + b1[2 * lane];
  float vy = ay * inv + b1[2 * lane + 1];
  vx = vx > 0.f ? vx : expm1f(vx);
  vy = vy > 0.f ? vy : expm1f(vy);
  float2 o; o.x = vx; o.y = vy;
  *(float2*)&out1[(size_t)wid * HID + 2 * lane] = o;
}

// ---------------- agg2: one wave per dst node; fused bias + log_softmax ----------
__global__ __launch_bounds__(256) void agg2_csr_kernel(const int* __restrict__ rowptr,
                                                       const int* __restrict__ csr_src,
                                                       const float* __restrict__ a_s,
                                                       const float* __restrict__ a_d,
                                                       const float* __restrict__ h2,
                                                       const float* __restrict__ b2,
                                                       float* __restrict__ out) {
  int wid = (blockIdx.x * 256 + threadIdx.x) >> 6;
  int lane = threadIdx.x & 63;
  if (wid >= N_NODES) return;
  const float adn = a_d[wid];
  int i = rowptr[wid], end = rowptr[wid + 1];
  float acc = 0.f, wsum = 0.f;
  for (; i + 1 < end; i += 2) {
    int s0 = csr_src[i], s1 = csr_src[i + 1];
    float h0 = h2[(size_t)s0 * OUT_F + lane];
    float h1v = h2[(size_t)s1 * OUT_F + lane];
    float w0 = __expf(lrelu(a_s[s0] + adn));
    float w1 = __expf(lrelu(a_s[s1] + adn));
    acc += w0 * h0 + w1 * h1v;
    wsum += w0 + w1;
  }
  if (i < end) {
    int s0 = csr_src[i];
    acc += __expf(lrelu(a_s[s0] + adn)) * h2[(size_t)s0 * OUT_F + lane];
    wsum += __expf(lrelu(a_s[s0] + adn));
  }
  float v = acc / (wsum + 1e-16f) + b2[lane];
  float m = v;
#pragma unroll
  for (int msk = 1; msk < 64; msk <<= 1) m = fmaxf(m, __shfl_xor(m, msk));
  float sm = __expf(v - m);
#pragma unroll
  for (int msk = 1; msk < 64; msk <<= 1) sm += __shfl_xor(sm, msk);
  out[(size_t)wid * OUT_F + lane] = v - m - __logf(sm);
}

extern "C" void kernel_launch(void* const* d_in, const int* in_sizes, int n_in,
                              void* d_out, int out_size, void* d_ws, size_t ws_size,
                              hipStream_t stream) {
  const float* x   = (const float*)d_in[0];
  const int* ei    = (const int*)d_in[1];
  const float* W1  = (const float*)d_in[2];
  const float* as1 = (const float*)d_in[3];
  const float* ad1 = (const float*)d_in[4];
  const float* b1  = (const float*)d_in[5];
  const float* W2  = (const float*)d_in[6];
  const float* as2 = (const float*)d_in[7];
  const float* ad2 = (const float*)d_in[8];
  const float* b2  = (const float*)d_in[9];
  float* out = (float*)d_out;

  float* ws = (float*)d_ws;
  float* h1     = ws;  ws += (size_t)N_NODES * HID;
  float* a_s1   = ws;  ws += (size_t)N_NODES * HEADS1;
  float* a_d1   = ws;  ws += (size_t)N_NODES * HEADS1;
  float* out1   = ws;  ws += (size_t)N_NODES * HID;
  float* h2     = ws;  ws += (size_t)N_NODES * OUT_F;
  float* a_s2   = ws;  ws += (size_t)N_NODES;
  float* a_d2   = ws;  ws += (size_t)N_NODES;
  unsigned short* W1t = (unsigned short*)ws;  ws += (IN_F * HID) / 2;   // 16B-aligned here
  unsigned short* W2t = (unsigned short*)ws;  ws += (HID * OUT_F) / 2;
  int* deg      = (int*)ws;  ws += (N_NODES + 1);
  int* rowptr   = (int*)ws;  ws += (N_NODES + 1);
  int* cursor   = (int*)ws;  ws += N_NODES;
  int* csr_src  = (int*)ws;  ws += ET;
  int* exq      = (int*)ws;  ws += N_NODES;
  int* bsum     = (int*)ws;  ws += NBLK;
  int* boff     = (int*)ws;  ws += NBLK;

  // ---- weight transpose+cast (tiny; independent) ----
  wt_kernel<<<dim3((IN_F * HID + 255) / 256), dim3(256), 0, stream>>>(W1, W1t, IN_F, HID);
  wt_kernel<<<dim3((HID * OUT_F + 255) / 256), dim3(256), 0, stream>>>(W2, W2t, HID, OUT_F);

  // ---- CSR build ----
  hipMemsetAsync(deg, 0, sizeof(int) * (N_NODES + 1), stream);
  deg_kernel<<<dim3((ET + 255) / 256), dim3(256), 0, stream>>>(ei, deg);
  scan1_kernel<<<dim3(NBLK), dim3(256), 0, stream>>>(deg, exq, bsum);
  scan2_kernel<<<dim3(1), dim3(256), 0, stream>>>(bsum, boff);
  scan3_kernel<<<dim3(NBLK), dim3(256), 0, stream>>>(exq, boff, rowptr, cursor);
  scatter_kernel<<<dim3((ET + 255) / 256), dim3(256), 0, stream>>>(ei, cursor, csr_src);

  // ---- layer 1 ----
  gemm1_mfma_kernel<<<dim3((N_NODES + 63) / 64), dim3(256), 0, stream>>>(x, W1t, h1);
  att1_kernel<<<dim3((N_NODES * 64 + 255) / 256), dim3(256), 0, stream>>>(h1, as1, ad1, a_s1, a_d1);
  agg1_csr_kernel<<<dim3((N_NODES + 3) / 4), dim3(256), 0, stream>>>(rowptr, csr_src, a_s1, a_d1, h1, b1, out1);

  // ---- layer 2 ----
  gemm2_mfma_kernel<<<dim3((N_NODES + 63) / 64), dim3(256), 0, stream>>>(out1, W2t, h2);
  att2_kernel<<<dim3((N_NODES * 64 + 255) / 256), dim3(256), 0, stream>>>(h2, as2, ad2, a_s2, a_d2);
  agg2_csr_kernel<<<dim3((N_NODES + 3) / 4), dim3(256), 0, stream>>>(rowptr, csr_src, a_s2, a_d2, h2, b2, out);
}

// Round 5
// 351.151 us; speedup vs baseline: 7.8970x; 1.1409x over previous
//
#include <hip/hip_runtime.h>
#include <math.h>

#define N_NODES 50000
#define E_EDGES 800000
#define ET (E_EDGES + N_NODES)   // edges + self loops
#define IN_F 256
#define HID 128
#define HEADS1 8
#define C1 16
#define OUT_F 64
#define NEG_SLOPE 0.2f
#define NBLK ((N_NODES + 255) / 256)   // 196 scan blocks

typedef __attribute__((ext_vector_type(8))) short short8;
typedef __attribute__((ext_vector_type(4))) float float4v;

__device__ __forceinline__ float lrelu(float v) { return v > 0.f ? v : NEG_SLOPE * v; }

__device__ __forceinline__ unsigned short f2bf(float f) {
  union { float f; unsigned u; } v; v.f = f;
  unsigned r = v.u + 0x7FFF + ((v.u >> 16) & 1);   // RNE
  return (unsigned short)(r >> 16);
}
__device__ __forceinline__ float bf2f(unsigned short u) {
  union { unsigned u; float f; } v; v.u = ((unsigned)u) << 16; return v.f;
}

// ---- W transpose+cast: Wt[n][k] bf16 from W[k][n] fp32 ----
__global__ __launch_bounds__(256) void wt_kernel(const float* __restrict__ W,
                                                 unsigned short* __restrict__ Wt,
                                                 int K, int Nc) {
  int i = blockIdx.x * 256 + threadIdx.x;
  if (i >= K * Nc) return;
  int n = i / K, k = i - n * K;
  Wt[i] = f2bf(W[k * Nc + n]);
}

// ---------------- GEMM1 (MFMA): h1bf[N,128] = x[N,256] @ W1 ----------------
__global__ __launch_bounds__(256) void gemm1_mfma_kernel(const float* __restrict__ x,
                                                         const unsigned short* __restrict__ W1t,
                                                         unsigned short* __restrict__ h1bf) {
  const int wave = blockIdx.x * 4 + (threadIdx.x >> 6);
  const int lane = threadIdx.x & 63;
  const int m0 = wave * 16;
  if (m0 >= N_NODES) return;
  const int lm = lane & 15;
  const int quad = lane >> 4;
  const int mrow = m0 + lm;
  const bool valid = mrow < N_NODES;
  const float* arow = x + (size_t)mrow * IN_F;

  float4v acc[8];
#pragma unroll
  for (int nt = 0; nt < 8; ++nt) acc[nt] = (float4v){0.f, 0.f, 0.f, 0.f};

#pragma unroll
  for (int k0 = 0; k0 < IN_F; k0 += 32) {
    short8 a;
    if (valid) {
      float4 f0 = *(const float4*)(arow + k0 + quad * 8);
      float4 f1 = *(const float4*)(arow + k0 + quad * 8 + 4);
      a[0] = f2bf(f0.x); a[1] = f2bf(f0.y); a[2] = f2bf(f0.z); a[3] = f2bf(f0.w);
      a[4] = f2bf(f1.x); a[5] = f2bf(f1.y); a[6] = f2bf(f1.z); a[7] = f2bf(f1.w);
    } else {
      a = (short8){0, 0, 0, 0, 0, 0, 0, 0};
    }
#pragma unroll
    for (int nt = 0; nt < 8; ++nt) {
      short8 b = *(const short8*)&W1t[(size_t)(nt * 16 + lm) * IN_F + k0 + quad * 8];
      acc[nt] = __builtin_amdgcn_mfma_f32_16x16x32_bf16(a, b, acc[nt], 0, 0, 0);
    }
  }

#pragma unroll
  for (int nt = 0; nt < 8; ++nt) {
#pragma unroll
    for (int r = 0; r < 4; ++r) {
      int row = m0 + quad * 4 + r;
      if (row < N_NODES) h1bf[(size_t)row * HID + nt * 16 + lm] = f2bf(acc[nt][r]);
    }
  }
}

// ---------------- GEMM2 (MFMA): h2bf[N,64] = out1bf[N,128] @ W2 ----------------
__global__ __launch_bounds__(256) void gemm2_mfma_kernel(const unsigned short* __restrict__ in,
                                                         const unsigned short* __restrict__ W2t,
                                                         unsigned short* __restrict__ h2bf) {
  const int wave = blockIdx.x * 4 + (threadIdx.x >> 6);
  const int lane = threadIdx.x & 63;
  const int m0 = wave * 16;
  if (m0 >= N_NODES) return;
  const int lm = lane & 15;
  const int quad = lane >> 4;
  const int mrow = m0 + lm;
  const bool valid = mrow < N_NODES;
  const unsigned short* arow = in + (size_t)mrow * HID;

  float4v acc[4];
#pragma unroll
  for (int nt = 0; nt < 4; ++nt) acc[nt] = (float4v){0.f, 0.f, 0.f, 0.f};

#pragma unroll
  for (int k0 = 0; k0 < HID; k0 += 32) {
    short8 a = valid ? *(const short8*)(arow + k0 + quad * 8)
                     : (short8){0, 0, 0, 0, 0, 0, 0, 0};
#pragma unroll
    for (int nt = 0; nt < 4; ++nt) {
      short8 b = *(const short8*)&W2t[(size_t)(nt * 16 + lm) * HID + k0 + quad * 8];
      acc[nt] = __builtin_amdgcn_mfma_f32_16x16x32_bf16(a, b, acc[nt], 0, 0, 0);
    }
  }

#pragma unroll
  for (int nt = 0; nt < 4; ++nt) {
#pragma unroll
    for (int r = 0; r < 4; ++r) {
      int row = m0 + quad * 4 + r;
      if (row < N_NODES) h2bf[(size_t)row * OUT_F + nt * 16 + lm] = f2bf(acc[nt][r]);
    }
  }
}

// ---------------- att1: a_s[N,8], a_d[N,8] from h1bf[N,128] ----------------
__global__ __launch_bounds__(256) void att1_kernel(const unsigned short* __restrict__ h1bf,
                                                   const float* __restrict__ att_src,
                                                   const float* __restrict__ att_dst,
                                                   float* __restrict__ a_s,
                                                   float* __restrict__ a_d) {
  int wid = (blockIdx.x * 256 + threadIdx.x) >> 6;
  int lane = threadIdx.x & 63;
  if (wid >= N_NODES) return;
  ushort2 hu = *(const ushort2*)&h1bf[(size_t)wid * HID + 2 * lane];
  float hx = bf2f(hu.x), hy = bf2f(hu.y);
  float2 as = *(const float2*)&att_src[2 * lane];
  float2 ad = *(const float2*)&att_dst[2 * lane];
  float vs = hx * as.x + hy * as.y;
  float vd = hx * ad.x + hy * ad.y;
  vs += __shfl_xor(vs, 1); vd += __shfl_xor(vd, 1);
  vs += __shfl_xor(vs, 2); vd += __shfl_xor(vd, 2);
  vs += __shfl_xor(vs, 4); vd += __shfl_xor(vd, 4);
  if ((lane & 7) == 0) {
    a_s[wid * HEADS1 + (lane >> 3)] = vs;
    a_d[wid * HEADS1 + (lane >> 3)] = vd;
  }
}

// ---------------- att2: a_s[N], a_d[N] from h2bf[N,64] ----------------
__global__ __launch_bounds__(256) void att2_kernel(const unsigned short* __restrict__ h2bf,
                                                   const float* __restrict__ att_src,
                                                   const float* __restrict__ att_dst,
                                                   float* __restrict__ a_s,
                                                   float* __restrict__ a_d) {
  int wid = (blockIdx.x * 256 + threadIdx.x) >> 6;
  int lane = threadIdx.x & 63;
  if (wid >= N_NODES) return;
  float h = bf2f(h2bf[(size_t)wid * OUT_F + lane]);
  float vs = h * att_src[lane];
  float vd = h * att_dst[lane];
#pragma unroll
  for (int m = 1; m < 64; m <<= 1) { vs += __shfl_xor(vs, m); vd += __shfl_xor(vd, m); }
  if (lane == 0) { a_s[wid] = vs; a_d[wid] = vd; }
}

// ---------------- CSR construction ----------------
__global__ __launch_bounds__(256) void deg_kernel(const int* __restrict__ ei,
                                                  int* __restrict__ deg) {
  int e = blockIdx.x * 256 + threadIdx.x;
  if (e >= ET) return;
  int d = (e < E_EDGES) ? ei[E_EDGES + e] : (e - E_EDGES);
  atomicAdd(&deg[d], 1);
}

__global__ __launch_bounds__(256) void scan1_kernel(const int* __restrict__ deg,
                                                    int* __restrict__ exq,
                                                    int* __restrict__ bsum) {
  __shared__ int sh[256];
  const int t = threadIdx.x;
  const int idx = blockIdx.x * 256 + t;
  int v = (idx < N_NODES) ? deg[idx] : 0;
  sh[t] = v;
  __syncthreads();
  for (int off = 1; off < 256; off <<= 1) {
    int u = (t >= off) ? sh[t - off] : 0;
    __syncthreads();
    sh[t] += u;
    __syncthreads();
  }
  if (idx < N_NODES) exq[idx] = sh[t] - v;
  if (t == 255) bsum[blockIdx.x] = sh[t];
}

__global__ __launch_bounds__(256) void scan2_kernel(const int* __restrict__ bsum,
                                                    int* __restrict__ boff) {
  __shared__ int sh[256];
  const int t = threadIdx.x;
  int v = (t < NBLK) ? bsum[t] : 0;
  sh[t] = v;
  __syncthreads();
  for (int off = 1; off < 256; off <<= 1) {
    int u = (t >= off) ? sh[t - off] : 0;
    __syncthreads();
    sh[t] += u;
    __syncthreads();
  }
  if (t < NBLK) boff[t] = sh[t] - v;
}

__global__ __launch_bounds__(256) void scan3_kernel(const int* __restrict__ exq,
                                                    const int* __restrict__ boff,
                                                    int* __restrict__ rowptr,
                                                    int* __restrict__ cursor) {
  const int idx = blockIdx.x * 256 + threadIdx.x;
  if (idx < N_NODES) {
    int r = exq[idx] + boff[blockIdx.x];
    rowptr[idx] = r;
    cursor[idx] = r;
  }
  if (idx == 0) rowptr[N_NODES] = ET;
}

__global__ __launch_bounds__(256) void scatter_kernel(const int* __restrict__ ei,
                                                      int* __restrict__ cursor,
                                                      int* __restrict__ csr_src) {
  int e = blockIdx.x * 256 + threadIdx.x;
  if (e >= ET) return;
  int s, d;
  if (e < E_EDGES) { s = ei[e]; d = ei[E_EDGES + e]; }
  else { s = d = e - E_EDGES; }
  int pos = atomicAdd(&cursor[d], 1);
  csr_src[pos] = s;
}

// ---------------- agg1: one wave per dst; bf16 gathers; fused norm+bias+ELU ----
__global__ __launch_bounds__(256) void agg1_csr_kernel(const int* __restrict__ rowptr,
                                                       const int* __restrict__ csr_src,
                                                       const float* __restrict__ a_s,
                                                       const float* __restrict__ a_d,
                                                       const unsigned short* __restrict__ h1bf,
                                                       const float* __restrict__ b1,
                                                       unsigned short* __restrict__ out1bf) {
  int wid = (blockIdx.x * 256 + threadIdx.x) >> 6;
  int lane = threadIdx.x & 63;                   // lane owns feats 2*lane, 2*lane+1
  if (wid >= N_NODES) return;
  const int head = lane >> 3;
  const float adn = a_d[(size_t)wid * HEADS1 + head];
  int i = rowptr[wid], end = rowptr[wid + 1];
  float ax = 0.f, ay = 0.f, wsum = 0.f;
  for (; i + 3 < end; i += 4) {
    int s0 = csr_src[i], s1 = csr_src[i + 1], s2 = csr_src[i + 2], s3 = csr_src[i + 3];
    float e0 = a_s[(size_t)s0 * HEADS1 + head];
    float e1 = a_s[(size_t)s1 * HEADS1 + head];
    float e2 = a_s[(size_t)s2 * HEADS1 + head];
    float e3 = a_s[(size_t)s3 * HEADS1 + head];
    ushort2 g0 = *(const ushort2*)&h1bf[(size_t)s0 * HID + 2 * lane];
    ushort2 g1 = *(const ushort2*)&h1bf[(size_t)s1 * HID + 2 * lane];
    ushort2 g2 = *(const ushort2*)&h1bf[(size_t)s2 * HID + 2 * lane];
    ushort2 g3 = *(const ushort2*)&h1bf[(size_t)s3 * HID + 2 * lane];
    float w0 = __expf(lrelu(e0 + adn));
    float w1 = __expf(lrelu(e1 + adn));
    float w2 = __expf(lrelu(e2 + adn));
    float w3 = __expf(lrelu(e3 + adn));
    ax += w0 * bf2f(g0.x) + w1 * bf2f(g1.x) + w2 * bf2f(g2.x) + w3 * bf2f(g3.x);
    ay += w0 * bf2f(g0.y) + w1 * bf2f(g1.y) + w2 * bf2f(g2.y) + w3 * bf2f(g3.y);
    wsum += (w0 + w1) + (w2 + w3);
  }
  for (; i < end; ++i) {
    int s0 = csr_src[i];
    ushort2 g0 = *(const ushort2*)&h1bf[(size_t)s0 * HID + 2 * lane];
    float w0 = __expf(lrelu(a_s[(size_t)s0 * HEADS1 + head] + adn));
    ax += w0 * bf2f(g0.x); ay += w0 * bf2f(g0.y); wsum += w0;
  }
  float inv = 1.f / (wsum + 1e-16f);
  float vx = ax * inv + b1[2 * lane];
  float vy = ay * inv + b1[2 * lane + 1];
  vx = vx > 0.f ? vx : expm1f(vx);
  vy = vy > 0.f ? vy : expm1f(vy);
  ushort2 o; o.x = f2bf(vx); o.y = f2bf(vy);
  *(ushort2*)&out1bf[(size_t)wid * HID + 2 * lane] = o;
}

// ---------------- agg2: one wave per dst; bf16 gathers; fused bias+log_softmax ----
__global__ __launch_bounds__(256) void agg2_csr_kernel(const int* __restrict__ rowptr,
                                                       const int* __restrict__ csr_src,
                                                       const float* __restrict__ a_s,
                                                       const float* __restrict__ a_d,
                                                       const unsigned short* __restrict__ h2bf,
                                                       const float* __restrict__ b2,
                                                       float* __restrict__ out) {
  int wid = (blockIdx.x * 256 + threadIdx.x) >> 6;
  int lane = threadIdx.x & 63;                   // lane owns feat `lane`
  if (wid >= N_NODES) return;
  const float adn = a_d[wid];
  int i = rowptr[wid], end = rowptr[wid + 1];
  float acc = 0.f, wsum = 0.f;
  for (; i + 3 < end; i += 4) {
    int s0 = csr_src[i], s1 = csr_src[i + 1], s2 = csr_src[i + 2], s3 = csr_src[i + 3];
    float e0 = a_s[s0], e1 = a_s[s1], e2 = a_s[s2], e3 = a_s[s3];
    unsigned short g0 = h2bf[(size_t)s0 * OUT_F + lane];
    unsigned short g1 = h2bf[(size_t)s1 * OUT_F + lane];
    unsigned short g2 = h2bf[(size_t)s2 * OUT_F + lane];
    unsigned short g3 = h2bf[(size_t)s3 * OUT_F + lane];
    float w0 = __expf(lrelu(e0 + adn));
    float w1 = __expf(lrelu(e1 + adn));
    float w2 = __expf(lrelu(e2 + adn));
    float w3 = __expf(lrelu(e3 + adn));
    acc += w0 * bf2f(g0) + w1 * bf2f(g1) + w2 * bf2f(g2) + w3 * bf2f(g3);
    wsum += (w0 + w1) + (w2 + w3);
  }
  for (; i < end; ++i) {
    int s0 = csr_src[i];
    float w0 = __expf(lrelu(a_s[s0] + adn));
    acc += w0 * bf2f(h2bf[(size_t)s0 * OUT_F + lane]);
    wsum += w0;
  }
  float v = acc / (wsum + 1e-16f) + b2[lane];
  float m = v;
#pragma unroll
  for (int msk = 1; msk < 64; msk <<= 1) m = fmaxf(m, __shfl_xor(m, msk));
  float sm = __expf(v - m);
#pragma unroll
  for (int msk = 1; msk < 64; msk <<= 1) sm += __shfl_xor(sm, msk);
  out[(size_t)wid * OUT_F + lane] = v - m - __logf(sm);
}

extern "C" void kernel_launch(void* const* d_in, const int* in_sizes, int n_in,
                              void* d_out, int out_size, void* d_ws, size_t ws_size,
                              hipStream_t stream) {
  const float* x   = (const float*)d_in[0];
  const int* ei    = (const int*)d_in[1];
  const float* W1  = (const float*)d_in[2];
  const float* as1 = (const float*)d_in[3];
  const float* ad1 = (const float*)d_in[4];
  const float* b1  = (const float*)d_in[5];
  const float* W2  = (const float*)d_in[6];
  const float* as2 = (const float*)d_in[7];
  const float* ad2 = (const float*)d_in[8];
  const float* b2  = (const float*)d_in[9];
  float* out = (float*)d_out;

  float* ws = (float*)d_ws;
  float* a_s1   = ws;  ws += (size_t)N_NODES * HEADS1;
  float* a_d1   = ws;  ws += (size_t)N_NODES * HEADS1;
  float* a_s2   = ws;  ws += (size_t)N_NODES;
  float* a_d2   = ws;  ws += (size_t)N_NODES;
  unsigned short* h1bf   = (unsigned short*)ws;  ws += (size_t)N_NODES * HID / 2;
  unsigned short* out1bf = (unsigned short*)ws;  ws += (size_t)N_NODES * HID / 2;
  unsigned short* h2bf   = (unsigned short*)ws;  ws += (size_t)N_NODES * OUT_F / 2;
  unsigned short* W1t = (unsigned short*)ws;  ws += (IN_F * HID) / 2;
  unsigned short* W2t = (unsigned short*)ws;  ws += (HID * OUT_F) / 2;
  int* deg      = (int*)ws;  ws += (N_NODES + 1);
  int* rowptr   = (int*)ws;  ws += (N_NODES + 1);
  int* cursor   = (int*)ws;  ws += N_NODES;
  int* csr_src  = (int*)ws;  ws += ET;
  int* exq      = (int*)ws;  ws += N_NODES;
  int* bsum     = (int*)ws;  ws += NBLK;
  int* boff     = (int*)ws;  ws += NBLK;

  // ---- weight transpose+cast (tiny; independent) ----
  wt_kernel<<<dim3((IN_F * HID + 255) / 256), dim3(256), 0, stream>>>(W1, W1t, IN_F, HID);
  wt_kernel<<<dim3((HID * OUT_F + 255) / 256), dim3(256), 0, stream>>>(W2, W2t, HID, OUT_F);

  // ---- CSR build ----
  hipMemsetAsync(deg, 0, sizeof(int) * (N_NODES + 1), stream);
  deg_kernel<<<dim3((ET + 255) / 256), dim3(256), 0, stream>>>(ei, deg);
  scan1_kernel<<<dim3(NBLK), dim3(256), 0, stream>>>(deg, exq, bsum);
  scan2_kernel<<<dim3(1), dim3(256), 0, stream>>>(bsum, boff);
  scan3_kernel<<<dim3(NBLK), dim3(256), 0, stream>>>(exq, boff, rowptr, cursor);
  scatter_kernel<<<dim3((ET + 255) / 256), dim3(256), 0, stream>>>(ei, cursor, csr_src);

  // ---- layer 1 ----
  gemm1_mfma_kernel<<<dim3((N_NODES + 63) / 64), dim3(256), 0, stream>>>(x, W1t, h1bf);
  att1_kernel<<<dim3((N_NODES * 64 + 255) / 256), dim3(256), 0, stream>>>(h1bf, as1, ad1, a_s1, a_d1);
  agg1_csr_kernel<<<dim3((N_NODES + 3) / 4), dim3(256), 0, stream>>>(rowptr, csr_src, a_s1, a_d1, h1bf, b1, out1bf);

  // ---- layer 2 ----
  gemm2_mfma_kernel<<<dim3((N_NODES + 63) / 64), dim3(256), 0, stream>>>(out1bf, W2t, h2bf);
  att2_kernel<<<dim3((N_NODES * 64 + 255) / 256), dim3(256), 0, stream>>>(h2bf, as2, ad2, a_s2, a_d2);
  agg2_csr_kernel<<<dim3((N_NODES + 3) / 4), dim3(256), 0, stream>>>(rowptr, csr_src, a_s2, a_d2, h2bf, b2, out);
}

// Round 6
// 345.478 us; speedup vs baseline: 8.0267x; 1.0164x over previous
//
#include <hip/hip_runtime.h>
#include <math.h>

#define N_NODES 50000
#define E_EDGES 800000
#define ET (E_EDGES + N_NODES)   // edges + self loops
#define IN_F 256
#define HID 128
#define HEADS1 8
#define C1 16
#define OUT_F 64
#define NEG_SLOPE 0.2f
#define NBLK ((N_NODES + 255) / 256)   // 196 scan blocks
#define NRANGE 8
#define RSPAN ((N_NODES + NRANGE - 1) / NRANGE)   // 6250
#define BPG 64                                     // blocks per range-group

typedef __attribute__((ext_vector_type(8))) short short8;
typedef __attribute__((ext_vector_type(4))) float float4v;

__device__ __forceinline__ float lrelu(float v) { return v > 0.f ? v : NEG_SLOPE * v; }

__device__ __forceinline__ unsigned short f2bf(float f) {
  union { float f; unsigned u; } v; v.f = f;
  unsigned r = v.u + 0x7FFF + ((v.u >> 16) & 1);   // RNE
  return (unsigned short)(r >> 16);
}
__device__ __forceinline__ float bf2f(unsigned short u) {
  union { unsigned u; float f; } v; v.u = ((unsigned)u) << 16; return v.f;
}

// ---- W transpose+cast: Wt[n][k] bf16 from W[k][n] fp32 ----
__global__ __launch_bounds__(256) void wt_kernel(const float* __restrict__ W,
                                                 unsigned short* __restrict__ Wt,
                                                 int K, int Nc) {
  int i = blockIdx.x * 256 + threadIdx.x;
  if (i >= K * Nc) return;
  int n = i / K, k = i - n * K;
  Wt[i] = f2bf(W[k * Nc + n]);
}

// ---------------- GEMM1 (MFMA): h1bf[N,128] = x[N,256] @ W1 ----------------
__global__ __launch_bounds__(256) void gemm1_mfma_kernel(const float* __restrict__ x,
                                                         const unsigned short* __restrict__ W1t,
                                                         unsigned short* __restrict__ h1bf) {
  const int wave = blockIdx.x * 4 + (threadIdx.x >> 6);
  const int lane = threadIdx.x & 63;
  const int m0 = wave * 16;
  if (m0 >= N_NODES) return;
  const int lm = lane & 15;
  const int quad = lane >> 4;
  const int mrow = m0 + lm;
  const bool valid = mrow < N_NODES;
  const float* arow = x + (size_t)mrow * IN_F;

  float4v acc[8];
#pragma unroll
  for (int nt = 0; nt < 8; ++nt) acc[nt] = (float4v){0.f, 0.f, 0.f, 0.f};

#pragma unroll
  for (int k0 = 0; k0 < IN_F; k0 += 32) {
    short8 a;
    if (valid) {
      float4 f0 = *(const float4*)(arow + k0 + quad * 8);
      float4 f1 = *(const float4*)(arow + k0 + quad * 8 + 4);
      a[0] = f2bf(f0.x); a[1] = f2bf(f0.y); a[2] = f2bf(f0.z); a[3] = f2bf(f0.w);
      a[4] = f2bf(f1.x); a[5] = f2bf(f1.y); a[6] = f2bf(f1.z); a[7] = f2bf(f1.w);
    } else {
      a = (short8){0, 0, 0, 0, 0, 0, 0, 0};
    }
#pragma unroll
    for (int nt = 0; nt < 8; ++nt) {
      short8 b = *(const short8*)&W1t[(size_t)(nt * 16 + lm) * IN_F + k0 + quad * 8];
      acc[nt] = __builtin_amdgcn_mfma_f32_16x16x32_bf16(a, b, acc[nt], 0, 0, 0);
    }
  }

#pragma unroll
  for (int nt = 0; nt < 8; ++nt) {
#pragma unroll
    for (int r = 0; r < 4; ++r) {
      int row = m0 + quad * 4 + r;
      if (row < N_NODES) h1bf[(size_t)row * HID + nt * 16 + lm] = f2bf(acc[nt][r]);
    }
  }
}

// ---------------- GEMM2 (MFMA): h2bf[N,64] = out1bf[N,128] @ W2 ----------------
__global__ __launch_bounds__(256) void gemm2_mfma_kernel(const unsigned short* __restrict__ in,
                                                         const unsigned short* __restrict__ W2t,
                                                         unsigned short* __restrict__ h2bf) {
  const int wave = blockIdx.x * 4 + (threadIdx.x >> 6);
  const int lane = threadIdx.x & 63;
  const int m0 = wave * 16;
  if (m0 >= N_NODES) return;
  const int lm = lane & 15;
  const int quad = lane >> 4;
  const int mrow = m0 + lm;
  const bool valid = mrow < N_NODES;
  const unsigned short* arow = in + (size_t)mrow * HID;

  float4v acc[4];
#pragma unroll
  for (int nt = 0; nt < 4; ++nt) acc[nt] = (float4v){0.f, 0.f, 0.f, 0.f};

#pragma unroll
  for (int k0 = 0; k0 < HID; k0 += 32) {
    short8 a = valid ? *(const short8*)(arow + k0 + quad * 8)
                     : (short8){0, 0, 0, 0, 0, 0, 0, 0};
#pragma unroll
    for (int nt = 0; nt < 4; ++nt) {
      short8 b = *(const short8*)&W2t[(size_t)(nt * 16 + lm) * HID + k0 + quad * 8];
      acc[nt] = __builtin_amdgcn_mfma_f32_16x16x32_bf16(a, b, acc[nt], 0, 0, 0);
    }
  }

#pragma unroll
  for (int nt = 0; nt < 4; ++nt) {
#pragma unroll
    for (int r = 0; r < 4; ++r) {
      int row = m0 + quad * 4 + r;
      if (row < N_NODES) h2bf[(size_t)row * OUT_F + nt * 16 + lm] = f2bf(acc[nt][r]);
    }
  }
}

// ---------------- att1: a_s[N,8], a_d[N,8] from h1bf[N,128] ----------------
__global__ __launch_bounds__(256) void att1_kernel(const unsigned short* __restrict__ h1bf,
                                                   const float* __restrict__ att_src,
                                                   const float* __restrict__ att_dst,
                                                   float* __restrict__ a_s,
                                                   float* __restrict__ a_d) {
  int wid = (blockIdx.x * 256 + threadIdx.x) >> 6;
  int lane = threadIdx.x & 63;
  if (wid >= N_NODES) return;
  ushort2 hu = *(const ushort2*)&h1bf[(size_t)wid * HID + 2 * lane];
  float hx = bf2f(hu.x), hy = bf2f(hu.y);
  float2 as = *(const float2*)&att_src[2 * lane];
  float2 ad = *(const float2*)&att_dst[2 * lane];
  float vs = hx * as.x + hy * as.y;
  float vd = hx * ad.x + hy * ad.y;
  vs += __shfl_xor(vs, 1); vd += __shfl_xor(vd, 1);
  vs += __shfl_xor(vs, 2); vd += __shfl_xor(vd, 2);
  vs += __shfl_xor(vs, 4); vd += __shfl_xor(vd, 4);
  if ((lane & 7) == 0) {
    a_s[wid * HEADS1 + (lane >> 3)] = vs;
    a_d[wid * HEADS1 + (lane >> 3)] = vd;
  }
}

// ---------------- att2: a_s[N], a_d[N] from h2bf[N,64] ----------------
__global__ __launch_bounds__(256) void att2_kernel(const unsigned short* __restrict__ h2bf,
                                                   const float* __restrict__ att_src,
                                                   const float* __restrict__ att_dst,
                                                   float* __restrict__ a_s,
                                                   float* __restrict__ a_d) {
  int wid = (blockIdx.x * 256 + threadIdx.x) >> 6;
  int lane = threadIdx.x & 63;
  if (wid >= N_NODES) return;
  float h = bf2f(h2bf[(size_t)wid * OUT_F + lane]);
  float vs = h * att_src[lane];
  float vd = h * att_dst[lane];
#pragma unroll
  for (int m = 1; m < 64; m <<= 1) { vs += __shfl_xor(vs, m); vd += __shfl_xor(vd, m); }
  if (lane == 0) { a_s[wid] = vs; a_d[wid] = vd; }
}

// ---------------- CSR construction (dst-range partitioned for L2 locality) ------
// group g = blockIdx % NRANGE handles dst in [g*RSPAN, (g+1)*RSPAN).
// Each group scans the full edge list (coalesced dst reads); its deg/cursor/csr
// slices are small enough to stay resident in one XCD's L2, so the random
// atomics and 4B scatter writes coalesce into full lines before eviction.
__global__ __launch_bounds__(256) void deg_part_kernel(const int* __restrict__ ei,
                                                       int* __restrict__ deg) {
  const int g = blockIdx.x & (NRANGE - 1);
  const int tg = (blockIdx.x >> 3) * 256 + threadIdx.x;   // thread idx in group
  const int lo = g * RSPAN, hi = lo + RSPAN;
  for (int e = tg; e < ET; e += BPG * 256) {
    int d = (e < E_EDGES) ? ei[E_EDGES + e] : (e - E_EDGES);
    if (d >= lo && d < hi) atomicAdd(&deg[d], 1);
  }
}

__global__ __launch_bounds__(256) void scatter_part_kernel(const int* __restrict__ ei,
                                                           int* __restrict__ cursor,
                                                           int* __restrict__ csr_src) {
  const int g = blockIdx.x & (NRANGE - 1);
  const int tg = (blockIdx.x >> 3) * 256 + threadIdx.x;
  const int lo = g * RSPAN, hi = lo + RSPAN;
  for (int e = tg; e < ET; e += BPG * 256) {
    int d = (e < E_EDGES) ? ei[E_EDGES + e] : (e - E_EDGES);
    if (d >= lo && d < hi) {
      int s = (e < E_EDGES) ? ei[e] : d;
      int pos = atomicAdd(&cursor[d], 1);
      csr_src[pos] = s;
    }
  }
}

__global__ __launch_bounds__(256) void scan1_kernel(const int* __restrict__ deg,
                                                    int* __restrict__ exq,
                                                    int* __restrict__ bsum) {
  __shared__ int sh[256];
  const int t = threadIdx.x;
  const int idx = blockIdx.x * 256 + t;
  int v = (idx < N_NODES) ? deg[idx] : 0;
  sh[t] = v;
  __syncthreads();
  for (int off = 1; off < 256; off <<= 1) {
    int u = (t >= off) ? sh[t - off] : 0;
    __syncthreads();
    sh[t] += u;
    __syncthreads();
  }
  if (idx < N_NODES) exq[idx] = sh[t] - v;
  if (t == 255) bsum[blockIdx.x] = sh[t];
}

__global__ __launch_bounds__(256) void scan2_kernel(const int* __restrict__ bsum,
                                                    int* __restrict__ boff) {
  __shared__ int sh[256];
  const int t = threadIdx.x;
  int v = (t < NBLK) ? bsum[t] : 0;
  sh[t] = v;
  __syncthreads();
  for (int off = 1; off < 256; off <<= 1) {
    int u = (t >= off) ? sh[t - off] : 0;
    __syncthreads();
    sh[t] += u;
    __syncthreads();
  }
  if (t < NBLK) boff[t] = sh[t] - v;
}

__global__ __launch_bounds__(256) void scan3_kernel(const int* __restrict__ exq,
                                                    const int* __restrict__ boff,
                                                    int* __restrict__ rowptr,
                                                    int* __restrict__ cursor) {
  const int idx = blockIdx.x * 256 + threadIdx.x;
  if (idx < N_NODES) {
    int r = exq[idx] + boff[blockIdx.x];
    rowptr[idx] = r;
    cursor[idx] = r;
  }
  if (idx == 0) rowptr[N_NODES] = ET;
}

// ---------------- agg1: one wave per dst; bf16 gathers; fused norm+bias+ELU ----
__global__ __launch_bounds__(256) void agg1_csr_kernel(const int* __restrict__ rowptr,
                                                       const int* __restrict__ csr_src,
                                                       const float* __restrict__ a_s,
                                                       const float* __restrict__ a_d,
                                                       const unsigned short* __restrict__ h1bf,
                                                       const float* __restrict__ b1,
                                                       unsigned short* __restrict__ out1bf) {
  int wid = (blockIdx.x * 256 + threadIdx.x) >> 6;
  int lane = threadIdx.x & 63;                   // lane owns feats 2*lane, 2*lane+1
  if (wid >= N_NODES) return;
  const int head = lane >> 3;
  const float adn = a_d[(size_t)wid * HEADS1 + head];
  int i = rowptr[wid], end = rowptr[wid + 1];
  float ax = 0.f, ay = 0.f, wsum = 0.f;
  for (; i + 3 < end; i += 4) {
    int s0 = csr_src[i], s1 = csr_src[i + 1], s2 = csr_src[i + 2], s3 = csr_src[i + 3];
    float e0 = a_s[(size_t)s0 * HEADS1 + head];
    float e1 = a_s[(size_t)s1 * HEADS1 + head];
    float e2 = a_s[(size_t)s2 * HEADS1 + head];
    float e3 = a_s[(size_t)s3 * HEADS1 + head];
    ushort2 g0 = *(const ushort2*)&h1bf[(size_t)s0 * HID + 2 * lane];
    ushort2 g1 = *(const ushort2*)&h1bf[(size_t)s1 * HID + 2 * lane];
    ushort2 g2 = *(const ushort2*)&h1bf[(size_t)s2 * HID + 2 * lane];
    ushort2 g3 = *(const ushort2*)&h1bf[(size_t)s3 * HID + 2 * lane];
    float w0 = __expf(lrelu(e0 + adn));
    float w1 = __expf(lrelu(e1 + adn));
    float w2 = __expf(lrelu(e2 + adn));
    float w3 = __expf(lrelu(e3 + adn));
    ax += w0 * bf2f(g0.x) + w1 * bf2f(g1.x) + w2 * bf2f(g2.x) + w3 * bf2f(g3.x);
    ay += w0 * bf2f(g0.y) + w1 * bf2f(g1.y) + w2 * bf2f(g2.y) + w3 * bf2f(g3.y);
    wsum += (w0 + w1) + (w2 + w3);
  }
  for (; i < end; ++i) {
    int s0 = csr_src[i];
    ushort2 g0 = *(const ushort2*)&h1bf[(size_t)s0 * HID + 2 * lane];
    float w0 = __expf(lrelu(a_s[(size_t)s0 * HEADS1 + head] + adn));
    ax += w0 * bf2f(g0.x); ay += w0 * bf2f(g0.y); wsum += w0;
  }
  float inv = 1.f / (wsum + 1e-16f);
  float vx = ax * inv + b1[2 * lane];
  float vy = ay * inv + b1[2 * lane + 1];
  vx = vx > 0.f ? vx : expm1f(vx);
  vy = vy > 0.f ? vy : expm1f(vy);
  ushort2 o; o.x = f2bf(vx); o.y = f2bf(vy);
  *(ushort2*)&out1bf[(size_t)wid * HID + 2 * lane] = o;
}

// ---------------- agg2: one wave per dst; bf16 gathers; fused bias+log_softmax ----
__global__ __launch_bounds__(256) void agg2_csr_kernel(const int* __restrict__ rowptr,
                                                       const int* __restrict__ csr_src,
                                                       const float* __restrict__ a_s,
                                                       const float* __restrict__ a_d,
                                                       const unsigned short* __restrict__ h2bf,
                                                       const float* __restrict__ b2,
                                                       float* __restrict__ out) {
  int wid = (blockIdx.x * 256 + threadIdx.x) >> 6;
  int lane = threadIdx.x & 63;                   // lane owns feat `lane`
  if (wid >= N_NODES) return;
  const float adn = a_d[wid];
  int i = rowptr[wid], end = rowptr[wid + 1];
  float acc = 0.f, wsum = 0.f;
  for (; i + 3 < end; i += 4) {
    int s0 = csr_src[i], s1 = csr_src[i + 1], s2 = csr_src[i + 2], s3 = csr_src[i + 3];
    float e0 = a_s[s0], e1 = a_s[s1], e2 = a_s[s2], e3 = a_s[s3];
    unsigned short g0 = h2bf[(size_t)s0 * OUT_F + lane];
    unsigned short g1 = h2bf[(size_t)s1 * OUT_F + lane];
    unsigned short g2 = h2bf[(size_t)s2 * OUT_F + lane];
    unsigned short g3 = h2bf[(size_t)s3 * OUT_F + lane];
    float w0 = __expf(lrelu(e0 + adn));
    float w1 = __expf(lrelu(e1 + adn));
    float w2 = __expf(lrelu(e2 + adn));
    float w3 = __expf(lrelu(e3 + adn));
    acc += w0 * bf2f(g0) + w1 * bf2f(g1) + w2 * bf2f(g2) + w3 * bf2f(g3);
    wsum += (w0 + w1) + (w2 + w3);
  }
  for (; i < end; ++i) {
    int s0 = csr_src[i];
    float w0 = __expf(lrelu(a_s[s0] + adn));
    acc += w0 * bf2f(h2bf[(size_t)s0 * OUT_F + lane]);
    wsum += w0;
  }
  float v = acc / (wsum + 1e-16f) + b2[lane];
  float m = v;
#pragma unroll
  for (int msk = 1; msk < 64; msk <<= 1) m = fmaxf(m, __shfl_xor(m, msk));
  float sm = __expf(v - m);
#pragma unroll
  for (int msk = 1; msk < 64; msk <<= 1) sm += __shfl_xor(sm, msk);
  out[(size_t)wid * OUT_F + lane] = v - m - __logf(sm);
}

extern "C" void kernel_launch(void* const* d_in, const int* in_sizes, int n_in,
                              void* d_out, int out_size, void* d_ws, size_t ws_size,
                              hipStream_t stream) {
  const float* x   = (const float*)d_in[0];
  const int* ei    = (const int*)d_in[1];
  const float* W1  = (const float*)d_in[2];
  const float* as1 = (const float*)d_in[3];
  const float* ad1 = (const float*)d_in[4];
  const float* b1  = (const float*)d_in[5];
  const float* W2  = (const float*)d_in[6];
  const float* as2 = (const float*)d_in[7];
  const float* ad2 = (const float*)d_in[8];
  const float* b2  = (const float*)d_in[9];
  float* out = (float*)d_out;

  float* ws = (float*)d_ws;
  float* a_s1   = ws;  ws += (size_t)N_NODES * HEADS1;
  float* a_d1   = ws;  ws += (size_t)N_NODES * HEADS1;
  float* a_s2   = ws;  ws += (size_t)N_NODES;
  float* a_d2   = ws;  ws += (size_t)N_NODES;
  unsigned short* h1bf   = (unsigned short*)ws;  ws += (size_t)N_NODES * HID / 2;
  unsigned short* out1bf = (unsigned short*)ws;  ws += (size_t)N_NODES * HID / 2;
  unsigned short* h2bf   = (unsigned short*)ws;  ws += (size_t)N_NODES * OUT_F / 2;
  unsigned short* W1t = (unsigned short*)ws;  ws += (IN_F * HID) / 2;
  unsigned short* W2t = (unsigned short*)ws;  ws += (HID * OUT_F) / 2;
  int* deg      = (int*)ws;  ws += (N_NODES + 1);
  int* rowptr   = (int*)ws;  ws += (N_NODES + 1);
  int* cursor   = (int*)ws;  ws += N_NODES;
  int* csr_src  = (int*)ws;  ws += ET;
  int* exq      = (int*)ws;  ws += N_NODES;
  int* bsum     = (int*)ws;  ws += NBLK;
  int* boff     = (int*)ws;  ws += NBLK;

  // ---- weight transpose+cast (tiny; independent) ----
  wt_kernel<<<dim3((IN_F * HID + 255) / 256), dim3(256), 0, stream>>>(W1, W1t, IN_F, HID);
  wt_kernel<<<dim3((HID * OUT_F + 255) / 256), dim3(256), 0, stream>>>(W2, W2t, HID, OUT_F);

  // ---- CSR build (dst-range partitioned) ----
  hipMemsetAsync(deg, 0, sizeof(int) * (N_NODES + 1), stream);
  deg_part_kernel<<<dim3(NRANGE * BPG), dim3(256), 0, stream>>>(ei, deg);
  scan1_kernel<<<dim3(NBLK), dim3(256), 0, stream>>>(deg, exq, bsum);
  scan2_kernel<<<dim3(1), dim3(256), 0, stream>>>(bsum, boff);
  scan3_kernel<<<dim3(NBLK), dim3(256), 0, stream>>>(exq, boff, rowptr, cursor);
  scatter_part_kernel<<<dim3(NRANGE * BPG), dim3(256), 0, stream>>>(ei, cursor, csr_src);

  // ---- layer 1 ----
  gemm1_mfma_kernel<<<dim3((N_NODES + 63) / 64), dim3(256), 0, stream>>>(x, W1t, h1bf);
  att1_kernel<<<dim3((N_NODES * 64 + 255) / 256), dim3(256), 0, stream>>>(h1bf, as1, ad1, a_s1, a_d1);
  agg1_csr_kernel<<<dim3((N_NODES + 3) / 4), dim3(256), 0, stream>>>(rowptr, csr_src, a_s1, a_d1, h1bf, b1, out1bf);

  // ---- layer 2 ----
  gemm2_mfma_kernel<<<dim3((N_NODES + 63) / 64), dim3(256), 0, stream>>>(out1bf, W2t, h2bf);
  att2_kernel<<<dim3((N_NODES * 64 + 255) / 256), dim3(256), 0, stream>>>(h2bf, as2, ad2, a_s2, a_d2);
  agg2_csr_kernel<<<dim3((N_NODES + 3) / 4), dim3(256), 0, stream>>>(rowptr, csr_src, a_s2, a_d2, h2bf, b2, out);
}

// Round 7
// 337.740 us; speedup vs baseline: 8.2106x; 1.0229x over previous
//
#include <hip/hip_runtime.h>
#include <math.h>

#define N_NODES 50000
#define E_EDGES 800000
#define ET (E_EDGES + N_NODES)   // edges + self loops
#define IN_F 256
#define HID 128
#define HEADS1 8
#define C1 16
#define OUT_F 64
#define NEG_SLOPE 0.2f
#define NBLK ((N_NODES + 255) / 256)   // 196 scan blocks
#define NRANGE 8
#define RSPAN ((N_NODES + NRANGE - 1) / NRANGE)   // 6250
#define BPG 256                                    // blocks per range-group

typedef __attribute__((ext_vector_type(8))) short short8;
typedef __attribute__((ext_vector_type(4))) float float4v;

__device__ __forceinline__ float lrelu(float v) { return v > 0.f ? v : NEG_SLOPE * v; }

__device__ __forceinline__ unsigned short f2bf(float f) {
  union { float f; unsigned u; } v; v.f = f;
  unsigned r = v.u + 0x7FFF + ((v.u >> 16) & 1);   // RNE
  return (unsigned short)(r >> 16);
}
__device__ __forceinline__ float bf2f(unsigned short u) {
  union { unsigned u; float f; } v; v.u = ((unsigned)u) << 16; return v.f;
}

// ---- W transpose+cast: Wt[n][k] bf16 from W[k][n] fp32 ----
__global__ __launch_bounds__(256) void wt_kernel(const float* __restrict__ W,
                                                 unsigned short* __restrict__ Wt,
                                                 int K, int Nc) {
  int i = blockIdx.x * 256 + threadIdx.x;
  if (i >= K * Nc) return;
  int n = i / K, k = i - n * K;
  Wt[i] = f2bf(W[k * Nc + n]);
}

// ---------------- GEMM1 (MFMA): h1bf[N,128] = x[N,256] @ W1 ----------------
__global__ __launch_bounds__(256) void gemm1_mfma_kernel(const float* __restrict__ x,
                                                         const unsigned short* __restrict__ W1t,
                                                         unsigned short* __restrict__ h1bf) {
  const int wave = blockIdx.x * 4 + (threadIdx.x >> 6);
  const int lane = threadIdx.x & 63;
  const int m0 = wave * 16;
  if (m0 >= N_NODES) return;
  const int lm = lane & 15;
  const int quad = lane >> 4;
  const int mrow = m0 + lm;
  const bool valid = mrow < N_NODES;
  const float* arow = x + (size_t)mrow * IN_F;

  float4v acc[8];
#pragma unroll
  for (int nt = 0; nt < 8; ++nt) acc[nt] = (float4v){0.f, 0.f, 0.f, 0.f};

#pragma unroll
  for (int k0 = 0; k0 < IN_F; k0 += 32) {
    short8 a;
    if (valid) {
      float4 f0 = *(const float4*)(arow + k0 + quad * 8);
      float4 f1 = *(const float4*)(arow + k0 + quad * 8 + 4);
      a[0] = f2bf(f0.x); a[1] = f2bf(f0.y); a[2] = f2bf(f0.z); a[3] = f2bf(f0.w);
      a[4] = f2bf(f1.x); a[5] = f2bf(f1.y); a[6] = f2bf(f1.z); a[7] = f2bf(f1.w);
    } else {
      a = (short8){0, 0, 0, 0, 0, 0, 0, 0};
    }
#pragma unroll
    for (int nt = 0; nt < 8; ++nt) {
      short8 b = *(const short8*)&W1t[(size_t)(nt * 16 + lm) * IN_F + k0 + quad * 8];
      acc[nt] = __builtin_amdgcn_mfma_f32_16x16x32_bf16(a, b, acc[nt], 0, 0, 0);
    }
  }

#pragma unroll
  for (int nt = 0; nt < 8; ++nt) {
#pragma unroll
    for (int r = 0; r < 4; ++r) {
      int row = m0 + quad * 4 + r;
      if (row < N_NODES) h1bf[(size_t)row * HID + nt * 16 + lm] = f2bf(acc[nt][r]);
    }
  }
}

// ---------------- GEMM2 (MFMA): h2bf[N,64] = out1bf[N,128] @ W2 ----------------
__global__ __launch_bounds__(256) void gemm2_mfma_kernel(const unsigned short* __restrict__ in,
                                                         const unsigned short* __restrict__ W2t,
                                                         unsigned short* __restrict__ h2bf) {
  const int wave = blockIdx.x * 4 + (threadIdx.x >> 6);
  const int lane = threadIdx.x & 63;
  const int m0 = wave * 16;
  if (m0 >= N_NODES) return;
  const int lm = lane & 15;
  const int quad = lane >> 4;
  const int mrow = m0 + lm;
  const bool valid = mrow < N_NODES;
  const unsigned short* arow = in + (size_t)mrow * HID;

  float4v acc[4];
#pragma unroll
  for (int nt = 0; nt < 4; ++nt) acc[nt] = (float4v){0.f, 0.f, 0.f, 0.f};

#pragma unroll
  for (int k0 = 0; k0 < HID; k0 += 32) {
    short8 a = valid ? *(const short8*)(arow + k0 + quad * 8)
                     : (short8){0, 0, 0, 0, 0, 0, 0, 0};
#pragma unroll
    for (int nt = 0; nt < 4; ++nt) {
      short8 b = *(const short8*)&W2t[(size_t)(nt * 16 + lm) * HID + k0 + quad * 8];
      acc[nt] = __builtin_amdgcn_mfma_f32_16x16x32_bf16(a, b, acc[nt], 0, 0, 0);
    }
  }

#pragma unroll
  for (int nt = 0; nt < 4; ++nt) {
#pragma unroll
    for (int r = 0; r < 4; ++r) {
      int row = m0 + quad * 4 + r;
      if (row < N_NODES) h2bf[(size_t)row * OUT_F + nt * 16 + lm] = f2bf(acc[nt][r]);
    }
  }
}

// ---------------- att1: a_s[N,8], a_d[N,8] from h1bf[N,128] ----------------
__global__ __launch_bounds__(256) void att1_kernel(const unsigned short* __restrict__ h1bf,
                                                   const float* __restrict__ att_src,
                                                   const float* __restrict__ att_dst,
                                                   float* __restrict__ a_s,
                                                   float* __restrict__ a_d) {
  int wid = (blockIdx.x * 256 + threadIdx.x) >> 6;
  int lane = threadIdx.x & 63;
  if (wid >= N_NODES) return;
  ushort2 hu = *(const ushort2*)&h1bf[(size_t)wid * HID + 2 * lane];
  float hx = bf2f(hu.x), hy = bf2f(hu.y);
  float2 as = *(const float2*)&att_src[2 * lane];
  float2 ad = *(const float2*)&att_dst[2 * lane];
  float vs = hx * as.x + hy * as.y;
  float vd = hx * ad.x + hy * ad.y;
  vs += __shfl_xor(vs, 1); vd += __shfl_xor(vd, 1);
  vs += __shfl_xor(vs, 2); vd += __shfl_xor(vd, 2);
  vs += __shfl_xor(vs, 4); vd += __shfl_xor(vd, 4);
  if ((lane & 7) == 0) {
    a_s[wid * HEADS1 + (lane >> 3)] = vs;
    a_d[wid * HEADS1 + (lane >> 3)] = vd;
  }
}

// ---------------- att2: a_s[N], a_d[N] from h2bf[N,64] ----------------
__global__ __launch_bounds__(256) void att2_kernel(const unsigned short* __restrict__ h2bf,
                                                   const float* __restrict__ att_src,
                                                   const float* __restrict__ att_dst,
                                                   float* __restrict__ a_s,
                                                   float* __restrict__ a_d) {
  int wid = (blockIdx.x * 256 + threadIdx.x) >> 6;
  int lane = threadIdx.x & 63;
  if (wid >= N_NODES) return;
  float h = bf2f(h2bf[(size_t)wid * OUT_F + lane]);
  float vs = h * att_src[lane];
  float vd = h * att_dst[lane];
#pragma unroll
  for (int m = 1; m < 64; m <<= 1) { vs += __shfl_xor(vs, m); vd += __shfl_xor(vd, m); }
  if (lane == 0) { a_s[wid] = vs; a_d[wid] = vd; }
}

// ---------------- CSR construction (dst-range partitioned for L2 locality) ------
__global__ __launch_bounds__(256) void deg_part_kernel(const int* __restrict__ ei,
                                                       int* __restrict__ deg) {
  const int g = blockIdx.x & (NRANGE - 1);
  const int tg = (blockIdx.x >> 3) * 256 + threadIdx.x;   // thread idx in group
  const int lo = g * RSPAN, hi = lo + RSPAN;
  for (int e = tg; e < ET; e += BPG * 256) {
    int d = (e < E_EDGES) ? ei[E_EDGES + e] : (e - E_EDGES);
    if (d >= lo && d < hi) atomicAdd(&deg[d], 1);
  }
}

__global__ __launch_bounds__(256) void scatter_part_kernel(const int* __restrict__ ei,
                                                           int* __restrict__ cursor,
                                                           int* __restrict__ csr_src) {
  const int g = blockIdx.x & (NRANGE - 1);
  const int tg = (blockIdx.x >> 3) * 256 + threadIdx.x;
  const int lo = g * RSPAN, hi = lo + RSPAN;
  for (int e = tg; e < ET; e += BPG * 256) {
    int d = (e < E_EDGES) ? ei[E_EDGES + e] : (e - E_EDGES);
    if (d >= lo && d < hi) {
      int s = (e < E_EDGES) ? ei[e] : d;
      int pos = atomicAdd(&cursor[d], 1);
      csr_src[pos] = s;
    }
  }
}

__global__ __launch_bounds__(256) void scan1_kernel(const int* __restrict__ deg,
                                                    int* __restrict__ exq,
                                                    int* __restrict__ bsum) {
  __shared__ int sh[256];
  const int t = threadIdx.x;
  const int idx = blockIdx.x * 256 + t;
  int v = (idx < N_NODES) ? deg[idx] : 0;
  sh[t] = v;
  __syncthreads();
  for (int off = 1; off < 256; off <<= 1) {
    int u = (t >= off) ? sh[t - off] : 0;
    __syncthreads();
    sh[t] += u;
    __syncthreads();
  }
  if (idx < N_NODES) exq[idx] = sh[t] - v;
  if (t == 255) bsum[blockIdx.x] = sh[t];
}

__global__ __launch_bounds__(256) void scan2_kernel(const int* __restrict__ bsum,
                                                    int* __restrict__ boff) {
  __shared__ int sh[256];
  const int t = threadIdx.x;
  int v = (t < NBLK) ? bsum[t] : 0;
  sh[t] = v;
  __syncthreads();
  for (int off = 1; off < 256; off <<= 1) {
    int u = (t >= off) ? sh[t - off] : 0;
    __syncthreads();
    sh[t] += u;
    __syncthreads();
  }
  if (t < NBLK) boff[t] = sh[t] - v;
}

__global__ __launch_bounds__(256) void scan3_kernel(const int* __restrict__ exq,
                                                    const int* __restrict__ boff,
                                                    int* __restrict__ rowptr,
                                                    int* __restrict__ cursor) {
  const int idx = blockIdx.x * 256 + threadIdx.x;
  if (idx < N_NODES) {
    int r = exq[idx] + boff[blockIdx.x];
    rowptr[idx] = r;
    cursor[idx] = r;
  }
  if (idx == 0) rowptr[N_NODES] = ET;
}

// ---------------- agg1: wave/dst; 8-edge unroll, dedup expf via shuffle ----------
// Dedup block: lane L computes w for (edge L>>3, head L&7) -> one expf per lane
// per 8 edges (was 8). Each lane then shuffles in the 8 weights for its own head.
__global__ __launch_bounds__(256) void agg1_csr_kernel(const int* __restrict__ rowptr,
                                                       const int* __restrict__ csr_src,
                                                       const float* __restrict__ a_s,
                                                       const float* __restrict__ a_d,
                                                       const unsigned short* __restrict__ h1bf,
                                                       const float* __restrict__ b1,
                                                       unsigned short* __restrict__ out1bf) {
  int wid = (blockIdx.x * 256 + threadIdx.x) >> 6;
  int lane = threadIdx.x & 63;                   // lane owns feats 2*lane, 2*lane+1
  if (wid >= N_NODES) return;
  const int head = lane >> 3;                    // own head (feats) AND dedup edge slot
  const int sub = lane & 7;                      // dedup head index
  const float adn  = a_d[(size_t)wid * HEADS1 + head];   // own-head dst logit (tail)
  const float adnb = a_d[(size_t)wid * HEADS1 + sub];    // dedup-head dst logit
  int i = rowptr[wid], end = rowptr[wid + 1];
  float ax = 0.f, ay = 0.f, wsum = 0.f;
  for (; i + 7 < end; i += 8) {
    int sj = csr_src[i + head];                  // edge slot = head (= lane>>3)
    float w = __expf(lrelu(a_s[(size_t)sj * HEADS1 + sub] + adnb));
    int sarr[8]; float warr[8];
#pragma unroll
    for (int j = 0; j < 8; ++j) {
      sarr[j] = __shfl(sj, j * 8);               // src of edge j
      warr[j] = __shfl(w, j * 8 + head);         // weight of edge j for my head
    }
    ushort2 g[8];
#pragma unroll
    for (int j = 0; j < 8; ++j)
      g[j] = *(const ushort2*)&h1bf[(size_t)sarr[j] * HID + 2 * lane];
#pragma unroll
    for (int j = 0; j < 8; ++j) {
      ax += warr[j] * bf2f(g[j].x);
      ay += warr[j] * bf2f(g[j].y);
      wsum += warr[j];
    }
  }
  for (; i < end; ++i) {
    int s0 = csr_src[i];
    ushort2 g0 = *(const ushort2*)&h1bf[(size_t)s0 * HID + 2 * lane];
    float w0 = __expf(lrelu(a_s[(size_t)s0 * HEADS1 + head] + adn));
    ax += w0 * bf2f(g0.x); ay += w0 * bf2f(g0.y); wsum += w0;
  }
  float inv = 1.f / (wsum + 1e-16f);
  float vx = ax * inv + b1[2 * lane];
  float vy = ay * inv + b1[2 * lane + 1];
  vx = vx > 0.f ? vx : expm1f(vx);
  vy = vy > 0.f ? vy : expm1f(vy);
  ushort2 o; o.x = f2bf(vx); o.y = f2bf(vy);
  *(ushort2*)&out1bf[(size_t)wid * HID + 2 * lane] = o;
}

// ---------------- agg2: wave/dst; 8-edge unroll, dedup expf (1 head) ------------
__global__ __launch_bounds__(256) void agg2_csr_kernel(const int* __restrict__ rowptr,
                                                       const int* __restrict__ csr_src,
                                                       const float* __restrict__ a_s,
                                                       const float* __restrict__ a_d,
                                                       const unsigned short* __restrict__ h2bf,
                                                       const float* __restrict__ b2,
                                                       float* __restrict__ out) {
  int wid = (blockIdx.x * 256 + threadIdx.x) >> 6;
  int lane = threadIdx.x & 63;                   // lane owns feat `lane`
  if (wid >= N_NODES) return;
  const float adn = a_d[wid];
  int i = rowptr[wid], end = rowptr[wid + 1];
  float acc = 0.f, wsum = 0.f;
  for (; i + 7 < end; i += 8) {
    int sme = csr_src[i + (lane & 7)];           // lane computes w for edge lane&7
    float w = __expf(lrelu(a_s[sme] + adn));
    int sarr[8]; float warr[8];
#pragma unroll
    for (int j = 0; j < 8; ++j) {
      sarr[j] = __shfl(sme, j);
      warr[j] = __shfl(w, j);
    }
    unsigned short g[8];
#pragma unroll
    for (int j = 0; j < 8; ++j)
      g[j] = h2bf[(size_t)sarr[j] * OUT_F + lane];
#pragma unroll
    for (int j = 0; j < 8; ++j) {
      acc += warr[j] * bf2f(g[j]);
      wsum += warr[j];
    }
  }
  for (; i < end; ++i) {
    int s0 = csr_src[i];
    float w0 = __expf(lrelu(a_s[s0] + adn));
    acc += w0 * bf2f(h2bf[(size_t)s0 * OUT_F + lane]);
    wsum += w0;
  }
  float v = acc / (wsum + 1e-16f) + b2[lane];
  float m = v;
#pragma unroll
  for (int msk = 1; msk < 64; msk <<= 1) m = fmaxf(m, __shfl_xor(m, msk));
  float sm = __expf(v - m);
#pragma unroll
  for (int msk = 1; msk < 64; msk <<= 1) sm += __shfl_xor(sm, msk);
  out[(size_t)wid * OUT_F + lane] = v - m - __logf(sm);
}

extern "C" void kernel_launch(void* const* d_in, const int* in_sizes, int n_in,
                              void* d_out, int out_size, void* d_ws, size_t ws_size,
                              hipStream_t stream) {
  const float* x   = (const float*)d_in[0];
  const int* ei    = (const int*)d_in[1];
  const float* W1  = (const float*)d_in[2];
  const float* as1 = (const float*)d_in[3];
  const float* ad1 = (const float*)d_in[4];
  const float* b1  = (const float*)d_in[5];
  const float* W2  = (const float*)d_in[6];
  const float* as2 = (const float*)d_in[7];
  const float* ad2 = (const float*)d_in[8];
  const float* b2  = (const float*)d_in[9];
  float* out = (float*)d_out;

  float* ws = (float*)d_ws;
  float* a_s1   = ws;  ws += (size_t)N_NODES * HEADS1;
  float* a_d1   = ws;  ws += (size_t)N_NODES * HEADS1;
  float* a_s2   = ws;  ws += (size_t)N_NODES;
  float* a_d2   = ws;  ws += (size_t)N_NODES;
  unsigned short* h1bf   = (unsigned short*)ws;  ws += (size_t)N_NODES * HID / 2;
  unsigned short* out1bf = (unsigned short*)ws;  ws += (size_t)N_NODES * HID / 2;
  unsigned short* h2bf   = (unsigned short*)ws;  ws += (size_t)N_NODES * OUT_F / 2;
  unsigned short* W1t = (unsigned short*)ws;  ws += (IN_F * HID) / 2;
  unsigned short* W2t = (unsigned short*)ws;  ws += (HID * OUT_F) / 2;
  int* deg      = (int*)ws;  ws += (N_NODES + 1);
  int* rowptr   = (int*)ws;  ws += (N_NODES + 1);
  int* cursor   = (int*)ws;  ws += N_NODES;
  int* csr_src  = (int*)ws;  ws += ET;
  int* exq      = (int*)ws;  ws += N_NODES;
  int* bsum     = (int*)ws;  ws += NBLK;
  int* boff     = (int*)ws;  ws += NBLK;

  // ---- weight transpose+cast (tiny; independent) ----
  wt_kernel<<<dim3((IN_F * HID + 255) / 256), dim3(256), 0, stream>>>(W1, W1t, IN_F, HID);
  wt_kernel<<<dim3((HID * OUT_F + 255) / 256), dim3(256), 0, stream>>>(W2, W2t, HID, OUT_F);

  // ---- CSR build (dst-range partitioned) ----
  hipMemsetAsync(deg, 0, sizeof(int) * (N_NODES + 1), stream);
  deg_part_kernel<<<dim3(NRANGE * BPG), dim3(256), 0, stream>>>(ei, deg);
  scan1_kernel<<<dim3(NBLK), dim3(256), 0, stream>>>(deg, exq, bsum);
  scan2_kernel<<<dim3(1), dim3(256), 0, stream>>>(bsum, boff);
  scan3_kernel<<<dim3(NBLK), dim3(256), 0, stream>>>(exq, boff, rowptr, cursor);
  scatter_part_kernel<<<dim3(NRANGE * BPG), dim3(256), 0, stream>>>(ei, cursor, csr_src);

  // ---- layer 1 ----
  gemm1_mfma_kernel<<<dim3((N_NODES + 63) / 64), dim3(256), 0, stream>>>(x, W1t, h1bf);
  att1_kernel<<<dim3((N_NODES * 64 + 255) / 256), dim3(256), 0, stream>>>(h1bf, as1, ad1, a_s1, a_d1);
  agg1_csr_kernel<<<dim3((N_NODES + 3) / 4), dim3(256), 0, stream>>>(rowptr, csr_src, a_s1, a_d1, h1bf, b1, out1bf);

  // ---- layer 2 ----
  gemm2_mfma_kernel<<<dim3((N_NODES + 63) / 64), dim3(256), 0, stream>>>(out1bf, W2t, h2bf);
  att2_kernel<<<dim3((N_NODES * 64 + 255) / 256), dim3(256), 0, stream>>>(h2bf, as2, ad2, a_s2, a_d2);
  agg2_csr_kernel<<<dim3((N_NODES + 3) / 4), dim3(256), 0, stream>>>(rowptr, csr_src, a_s2, a_d2, h2bf, b2, out);
}